// Round 1
// baseline (3772.414 us; speedup 1.0000x reference)
//
#include <hip/hip_runtime.h>
#include <hip/hip_bf16.h>

// ---------- helpers ----------
__device__ inline float bf2f(unsigned short u){
  union { unsigned int i; float f; } v; v.i = ((unsigned int)u)<<16; return v.f;
}
__device__ inline unsigned short f2bf(float f){
  union { float f; unsigned int u; } v; v.f = f;
  unsigned int r = v.u + 0x7fffu + ((v.u>>16)&1u);
  return (unsigned short)(r>>16);
}

#define D_DIM 768
#define NTOK 1024
#define NSLOT 16
#define NB 32
#define HDIM 512   // H*DH
#define INNER 3072
#define SCALE_D 0.03608439182435161f   // 768^-0.5
#define SCALE_H 0.125f                 // 64^-0.5

// ---------- generic bf16 GEMM: C[M,N] = A[M,K] @ B[K,N] (+ optional f32 residual) ----------
// tiles: 64x64, BK=32, 256 threads, 4x4 micro-tile. M%64==0, N%64==0, K%32==0.
template<bool OUT_BF16, bool RES>
__global__ __launch_bounds__(256) void gemm_k(
    const unsigned short* __restrict__ A,
    const unsigned short* __restrict__ B,
    void* __restrict__ Cout,
    const float* __restrict__ Res,
    int M, int N, int K)
{
  __shared__ float As[32][68];  // As[k][m] (transposed)
  __shared__ float Bs[32][68];  // Bs[k][n]
  const int tid = threadIdx.x;
  const int m0 = blockIdx.x*64, n0 = blockIdx.y*64;
  const int ty = tid>>4, tx = tid&15;
  const int mA = tid>>2, kq = tid&3;   // A load: row mA, 8 bf16 at k0+kq*8
  const int kB = tid>>3, nq = tid&7;   // B load: row kB, 8 bf16 at n0+nq*8
  float acc[4][4] = {};
  for (int k0=0; k0<K; k0+=32){
    const unsigned short* ap = A + (size_t)(m0+mA)*K + (k0 + kq*8);
    ushort4 a0 = *(const ushort4*)ap;
    ushort4 a1 = *(const ushort4*)(ap+4);
    const int kk = kq*8;
    As[kk+0][mA]=bf2f(a0.x); As[kk+1][mA]=bf2f(a0.y);
    As[kk+2][mA]=bf2f(a0.z); As[kk+3][mA]=bf2f(a0.w);
    As[kk+4][mA]=bf2f(a1.x); As[kk+5][mA]=bf2f(a1.y);
    As[kk+6][mA]=bf2f(a1.z); As[kk+7][mA]=bf2f(a1.w);
    const unsigned short* bp = B + (size_t)(k0+kB)*N + (n0 + nq*8);
    ushort4 b0 = *(const ushort4*)bp;
    ushort4 b1 = *(const ushort4*)(bp+4);
    float4 f0 = { bf2f(b0.x), bf2f(b0.y), bf2f(b0.z), bf2f(b0.w) };
    float4 f1 = { bf2f(b1.x), bf2f(b1.y), bf2f(b1.z), bf2f(b1.w) };
    *(float4*)&Bs[kB][nq*8]   = f0;
    *(float4*)&Bs[kB][nq*8+4] = f1;
    __syncthreads();
    #pragma unroll 8
    for (int k2=0;k2<32;++k2){
      float4 av = *(const float4*)&As[k2][ty*4];
      float4 bv = *(const float4*)&Bs[k2][tx*4];
      float a[4]={av.x,av.y,av.z,av.w};
      float b[4]={bv.x,bv.y,bv.z,bv.w};
      #pragma unroll
      for (int i=0;i<4;++i)
        #pragma unroll
        for (int j=0;j<4;++j)
          acc[i][j] += a[i]*b[j];
    }
    __syncthreads();
  }
  #pragma unroll
  for (int i=0;i<4;++i){
    int m = m0 + ty*4 + i;
    #pragma unroll
    for (int j=0;j<4;++j){
      int n = n0 + tx*4 + j;
      float c = acc[i][j];
      if (RES) c += Res[(size_t)m*N + n];
      if (OUT_BF16) ((unsigned short*)Cout)[(size_t)m*N+n] = f2bf(c);
      else          ((float*)Cout)[(size_t)m*N+n] = c;
    }
  }
}

// ---------- LayerNorm over rows of width 768 ----------
template<bool ADD, bool OBF>
__global__ __launch_bounds__(256) void ln_k(
    const float* __restrict__ X, const float* __restrict__ X2,
    const float* __restrict__ g, const float* __restrict__ bb,
    void* __restrict__ out)
{
  __shared__ float rs[256], rss[256];
  const int row = blockIdx.x, tid = threadIdx.x;
  const float* x = X + (size_t)row*D_DIM;
  float vals[3]; float s=0.f, ss=0.f;
  #pragma unroll
  for (int t=0;t<3;++t){
    int c = tid + t*256;
    float v = x[c];
    if (ADD) v += X2[(size_t)row*D_DIM + c];
    vals[t]=v; s+=v; ss+=v*v;
  }
  rs[tid]=s; rss[tid]=ss; __syncthreads();
  for (int off=128; off>0; off>>=1){
    if (tid<off){ rs[tid]+=rs[tid+off]; rss[tid]+=rss[tid+off]; }
    __syncthreads();
  }
  float mean = rs[0]*(1.0f/768.0f);
  float var  = rss[0]*(1.0f/768.0f) - mean*mean;
  float inv  = rsqrtf(var + 1e-5f);
  #pragma unroll
  for (int t=0;t<3;++t){
    int c = tid + t*256;
    float y = (vals[t]-mean)*inv*g[c] + bb[c];
    if (OBF) ((unsigned short*)out)[(size_t)row*D_DIM + c] = f2bf(y);
    else     ((float*)out)[(size_t)row*D_DIM + c] = y;
  }
}

// ---------- slots init ----------
__global__ __launch_bounds__(256) void slots_init_k(
    const float* __restrict__ noise, const float* __restrict__ mu,
    const float* __restrict__ ls, float* __restrict__ slots)
{
  int idx = blockIdx.x*256 + threadIdx.x;   // 512*768
  int d = idx % D_DIM;
  slots[idx] = mu[d] + expf(ls[d]) * noise[idx];
}

// ---------- dots + inverted softmax (over slot axis) + EPS + rowsum ----------
// grid (32, 16): batch x 64-col j-tile. attn_pre[b,i,j] = softmax_i(dots)+1e-8
__global__ __launch_bounds__(256) void dots_k(
    const unsigned short* __restrict__ Q,   // [32,16,768] bf16
    const unsigned short* __restrict__ Km,  // [32,1024,768] bf16
    float* __restrict__ attn,               // [32,16,1024]
    float* __restrict__ rowsum)             // [512]
{
  __shared__ float qs[16][68];
  __shared__ float ks[64][68];
  __shared__ float ds[16][68];
  const int b = blockIdx.x, j0 = blockIdx.y*64;
  const int tid = threadIdx.x;
  const int ci = tid & 15;
  const int cj = (tid>>4)*4;
  float acc[4] = {0.f,0.f,0.f,0.f};
  for (int d0=0; d0<D_DIM; d0+=64){
    { // q tile 16x64
      int i = tid>>4, dd=(tid&15)*4;
      const unsigned short* p = Q + ((size_t)(b*NSLOT+i))*D_DIM + d0 + dd;
      ushort4 u = *(const ushort4*)p;
      float4 f = { bf2f(u.x), bf2f(u.y), bf2f(u.z), bf2f(u.w) };
      *(float4*)&qs[i][dd] = f;
    }
    { // k tile 64x64
      int jj = tid>>2, base=(tid&3)*16;
      const unsigned short* p = Km + ((size_t)(b*NTOK + j0 + jj))*D_DIM + d0 + base;
      #pragma unroll
      for (int t=0;t<4;++t){
        ushort4 u = *(const ushort4*)(p + t*4);
        float4 f = { bf2f(u.x), bf2f(u.y), bf2f(u.z), bf2f(u.w) };
        *(float4*)&ks[jj][base + t*4] = f;
      }
    }
    __syncthreads();
    #pragma unroll 8
    for (int dd=0; dd<64; ++dd){
      float qv = qs[ci][dd];
      acc[0]+=qv*ks[cj+0][dd]; acc[1]+=qv*ks[cj+1][dd];
      acc[2]+=qv*ks[cj+2][dd]; acc[3]+=qv*ks[cj+3][dd];
    }
    __syncthreads();
  }
  #pragma unroll
  for (int t=0;t<4;++t) ds[ci][cj+t] = acc[t]*SCALE_D;
  __syncthreads();
  if (tid < 64){
    int jj = tid;
    float mx = -1e30f;
    #pragma unroll
    for (int i=0;i<16;++i) mx = fmaxf(mx, ds[i][jj]);
    float e[16]; float sm=0.f;
    #pragma unroll
    for (int i=0;i<16;++i){ e[i]=__expf(ds[i][jj]-mx); sm+=e[i]; }
    float inv = 1.0f/sm;
    #pragma unroll
    for (int i=0;i<16;++i){
      float a = e[i]*inv + 1e-8f;
      ds[i][jj] = a;
      attn[((size_t)b*NSLOT+i)*NTOK + j0 + jj] = a;
    }
  }
  __syncthreads();
  if (tid < 16){
    float s = 0.f;
    #pragma unroll 8
    for (int jj=0;jj<64;++jj) s += ds[tid][jj];
    atomicAdd(&rowsum[b*NSLOT + tid], s);
  }
}

// ---------- updates = (attn_pre @ V) / rowsum ----------
// grid (32, 6): batch x 128-wide d-tile
__global__ __launch_bounds__(256) void attnv_k(
    const float* __restrict__ attn,   // [32,16,1024]
    const float* __restrict__ rowsum, // [512]
    const unsigned short* __restrict__ V, // [32,1024,768] bf16
    float* __restrict__ upd)          // [32,16,768]
{
  __shared__ float as_[16][68];
  __shared__ float vs[64][132];
  const int b = blockIdx.x, dbase = blockIdx.y*128;
  const int tid = threadIdx.x;
  const int ci = tid>>4;        // i
  const int cd = (tid&15)*8;    // d within 128
  float acc[8] = {};
  for (int j0=0; j0<NTOK; j0+=64){
    { // attn tile 16x64
      int i = tid>>4, jj=(tid&15)*4;
      float4 a4 = *(const float4*)&attn[((size_t)b*NSLOT+i)*NTOK + j0 + jj];
      *(float4*)&as_[i][jj] = a4;
    }
    { // V tile 64x128
      int jj = tid>>2, ds0=(tid&3)*32;
      const unsigned short* p = V + ((size_t)(b*NTOK+j0+jj))*D_DIM + dbase + ds0;
      #pragma unroll
      for (int t=0;t<8;++t){
        ushort4 u = *(const ushort4*)(p + t*4);
        float4 f = { bf2f(u.x), bf2f(u.y), bf2f(u.z), bf2f(u.w) };
        *(float4*)&vs[jj][ds0 + t*4] = f;
      }
    }
    __syncthreads();
    #pragma unroll 4
    for (int jj=0;jj<64;++jj){
      float av = as_[ci][jj];
      #pragma unroll
      for (int t=0;t<8;++t) acc[t] += av*vs[jj][cd+t];
    }
    __syncthreads();
  }
  float inv = 1.0f / rowsum[b*NSLOT + ci];
  #pragma unroll
  for (int t=0;t<8;++t)
    upd[((size_t)b*NSLOT+ci)*D_DIM + dbase + cd + t] = acc[t]*inv;
}

// ---------- encoder self-attention (tiny: 16x16 per (b,h)) ----------
__global__ __launch_bounds__(256) void encattn_k(
    const unsigned short* __restrict__ QA, // [32,16,512] bf16
    const unsigned short* __restrict__ KA,
    const unsigned short* __restrict__ VA,
    unsigned short* __restrict__ O)        // [32,16,512] bf16
{
  __shared__ float qs[16][68], ks[16][68], vs[16][68], ps[16][20];
  const int b = blockIdx.x, h = blockIdx.y;
  const int tid = threadIdx.x;
  {
    int i = tid>>4, dd=(tid&15)*4;
    size_t base = ((size_t)(b*NSLOT+i))*HDIM + h*64 + dd;
    ushort4 uq = *(const ushort4*)(QA + base);
    ushort4 uk = *(const ushort4*)(KA + base);
    ushort4 uv = *(const ushort4*)(VA + base);
    float4 fq = { bf2f(uq.x), bf2f(uq.y), bf2f(uq.z), bf2f(uq.w) };
    float4 fk = { bf2f(uk.x), bf2f(uk.y), bf2f(uk.z), bf2f(uk.w) };
    float4 fv = { bf2f(uv.x), bf2f(uv.y), bf2f(uv.z), bf2f(uv.w) };
    *(float4*)&qs[i][dd]=fq; *(float4*)&ks[i][dd]=fk; *(float4*)&vs[i][dd]=fv;
  }
  __syncthreads();
  {
    int i = tid>>4, j = tid&15;
    float s=0.f;
    #pragma unroll 8
    for (int d=0; d<64; ++d) s += qs[i][d]*ks[j][d];
    ps[i][j] = s*SCALE_H;
  }
  __syncthreads();
  if (tid < 16){
    int i = tid;
    float mx=-1e30f;
    #pragma unroll
    for (int j=0;j<16;++j) mx = fmaxf(mx, ps[i][j]);
    float sm=0.f;
    #pragma unroll
    for (int j=0;j<16;++j){ float e=__expf(ps[i][j]-mx); ps[i][j]=e; sm+=e; }
    float inv=1.0f/sm;
    #pragma unroll
    for (int j=0;j<16;++j) ps[i][j]*=inv;
  }
  __syncthreads();
  {
    int i = tid>>4, dq=(tid&15)*4;
    float a0=0,a1=0,a2=0,a3=0;
    #pragma unroll
    for (int j=0;j<16;++j){
      float p = ps[i][j];
      a0+=p*vs[j][dq+0]; a1+=p*vs[j][dq+1]; a2+=p*vs[j][dq+2]; a3+=p*vs[j][dq+3];
    }
    size_t base = ((size_t)(b*NSLOT+i))*HDIM + h*64 + dq;
    O[base+0]=f2bf(a0); O[base+1]=f2bf(a1); O[base+2]=f2bf(a2); O[base+3]=f2bf(a3);
  }
}

// ---------- GLU activation: act = u * silu(g) ----------
__global__ __launch_bounds__(256) void glu_k(
    const float* __restrict__ fw, unsigned short* __restrict__ act)
{
  int idx = blockIdx.x*256 + threadIdx.x;   // 512*3072
  int r = idx / INNER, c = idx % INNER;
  float u = fw[(size_t)r*(2*INNER) + c];
  float g = fw[(size_t)r*(2*INNER) + INNER + c];
  float sg = g / (1.0f + __expf(-g));
  act[idx] = f2bf(u*sg);
}

// ---------- f32 -> bf16 cast ----------
__global__ __launch_bounds__(256) void cast_k(
    const float* __restrict__ in, unsigned short* __restrict__ out, int n)
{
  int i = blockIdx.x*256 + threadIdx.x;
  if (i < n) out[i] = f2bf(in[i]);
}

// ---------- attn_map output: out[b,j,i] = attn[b,i,j]/rowsum[b,i] ----------
__global__ __launch_bounds__(256) void attnout_k(
    const float* __restrict__ attn, const float* __restrict__ rowsum,
    float* __restrict__ out)
{
  int idx = blockIdx.x*256 + threadIdx.x;  // 32*1024*16
  int i = idx & 15;
  int j = (idx >> 4) & 1023;
  int b = idx >> 14;
  out[idx] = attn[((size_t)b*NSLOT+i)*NTOK + j] / rowsum[b*NSLOT + i];
}

extern "C" void kernel_launch(void* const* d_in, const int* in_sizes, int n_in,
                              void* d_out, int out_size, void* d_ws, size_t ws_size,
                              hipStream_t stream) {
  const float* x        = (const float*)d_in[0];
  const float* noise    = (const float*)d_in[1];
  const float* init_mu  = (const float*)d_in[2];
  const float* init_ls  = (const float*)d_in[3];
  const float* Wk       = (const float*)d_in[4];
  const float* Wv       = (const float*)d_in[5];
  const float* Wq       = (const float*)d_in[6];
  const float* ni_g     = (const float*)d_in[7];
  const float* ni_b     = (const float*)d_in[8];
  const float* ns_g     = (const float*)d_in[9];
  const float* ns_b     = (const float*)d_in[10];
  const float* nica_g   = (const float*)d_in[11];
  const float* nica_b   = (const float*)d_in[12];
  const float* ln1_g    = (const float*)d_in[13];
  const float* ln1_b    = (const float*)d_in[14];
  const float* Wq_a     = (const float*)d_in[15];
  const float* Wk_a     = (const float*)d_in[16];
  const float* Wv_a     = (const float*)d_in[17];
  const float* Wo_a     = (const float*)d_in[18];
  const float* ln2_g    = (const float*)d_in[19];
  const float* ln2_b    = (const float*)d_in[20];
  const float* W1       = (const float*)d_in[21];
  const float* W2       = (const float*)d_in[22];
  const float* lnf_g    = (const float*)d_in[23];
  const float* lnf_b    = (const float*)d_in[24];

  // ---- workspace layout ----
  char* w = (char*)d_ws;
  size_t off = 0;
  auto alloc = [&](size_t bytes)->char*{
    char* p = w + off; off += (bytes + 255) & ~(size_t)255; return p;
  };
  unsigned short* xn_bf = (unsigned short*)alloc((size_t)NB*NTOK*D_DIM*2);
  unsigned short* k_bf  = (unsigned short*)alloc((size_t)NB*NTOK*D_DIM*2);
  unsigned short* v_bf  = (unsigned short*)alloc((size_t)NB*NTOK*D_DIM*2);
  unsigned short* Wk_bf  = (unsigned short*)alloc(768*768*2);
  unsigned short* Wv_bf  = (unsigned short*)alloc(768*768*2);
  unsigned short* Wq_bf  = (unsigned short*)alloc(768*768*2);
  unsigned short* Wqa_bf = (unsigned short*)alloc(768*512*2);
  unsigned short* Wka_bf = (unsigned short*)alloc(768*512*2);
  unsigned short* Wva_bf = (unsigned short*)alloc(768*512*2);
  unsigned short* Woa_bf = (unsigned short*)alloc(512*768*2);
  unsigned short* W1_bf  = (unsigned short*)alloc(768*6144*2);
  unsigned short* W2_bf  = (unsigned short*)alloc(3072*768*2);
  float* slots = (float*)alloc(512*768*4);
  float* hbuf  = (float*)alloc(512*768*4);
  float* upd   = (float*)alloc(512*768*4);
  unsigned short* tmp_bf = (unsigned short*)alloc(512*768*2);
  unsigned short* q_bf   = (unsigned short*)alloc(512*768*2);
  unsigned short* qa_bf  = (unsigned short*)alloc(512*512*2);
  unsigned short* ka_bf  = (unsigned short*)alloc(512*512*2);
  unsigned short* va_bf  = (unsigned short*)alloc(512*512*2);
  unsigned short* o_bf   = (unsigned short*)alloc(512*512*2);
  float* fw    = (float*)alloc((size_t)512*6144*4);
  unsigned short* act_bf = (unsigned short*)alloc((size_t)512*3072*2);
  float* attn_pre = (float*)alloc((size_t)NB*NSLOT*NTOK*4);
  float* rowsum   = (float*)alloc(512*4);

  // ---- cast weights to bf16 ----
  auto cast = [&](const float* src, unsigned short* dst, int n){
    cast_k<<<(n+255)/256, 256, 0, stream>>>(src, dst, n);
  };
  cast(Wk,   Wk_bf,  768*768);
  cast(Wv,   Wv_bf,  768*768);
  cast(Wq,   Wq_bf,  768*768);
  cast(Wq_a, Wqa_bf, 768*512);
  cast(Wk_a, Wka_bf, 768*512);
  cast(Wv_a, Wva_bf, 768*512);
  cast(Wo_a, Woa_bf, 512*768);
  cast(W1,   W1_bf,  768*6144);
  cast(W2,   W2_bf,  3072*768);

  // ---- xn = LN(x); k = xn@Wk; v = xn@Wv ----
  ln_k<false,true><<<NB*NTOK, 256, 0, stream>>>(x, nullptr, ni_g, ni_b, xn_bf);
  gemm_k<true,false><<<dim3(NB*NTOK/64, 768/64), 256, 0, stream>>>(xn_bf, Wk_bf, k_bf, nullptr, NB*NTOK, 768, 768);
  gemm_k<true,false><<<dim3(NB*NTOK/64, 768/64), 256, 0, stream>>>(xn_bf, Wv_bf, v_bf, nullptr, NB*NTOK, 768, 768);

  // ---- slots init ----
  slots_init_k<<<512*768/256, 256, 0, stream>>>(noise, init_mu, init_ls, slots);

  // ---- 4 iterations ----
  for (int it=0; it<4; ++it){
    // q = LN(slots, ns) @ Wq
    ln_k<false,true><<<512, 256, 0, stream>>>(slots, nullptr, ns_g, ns_b, tmp_bf);
    gemm_k<true,false><<<dim3(8, 12), 256, 0, stream>>>(tmp_bf, Wq_bf, q_bf, nullptr, 512, 768, 768);
    // dots + inverted softmax
    hipMemsetAsync(rowsum, 0, 512*4, stream);
    dots_k<<<dim3(NB, NTOK/64), 256, 0, stream>>>(q_bf, k_bf, attn_pre, rowsum);
    // updates = (attn/rowsum) @ v
    attnv_k<<<dim3(NB, D_DIM/128), 256, 0, stream>>>(attn_pre, rowsum, v_bf, upd);
    // h = LN(slots + updates, nica)
    ln_k<true,false><<<512, 256, 0, stream>>>(slots, upd, nica_g, nica_b, hbuf);
    // encoder: a = LN(h, ln1); qa/ka/va
    ln_k<false,true><<<512, 256, 0, stream>>>(hbuf, nullptr, ln1_g, ln1_b, tmp_bf);
    gemm_k<true,false><<<dim3(8, 8), 256, 0, stream>>>(tmp_bf, Wqa_bf, qa_bf, nullptr, 512, 512, 768);
    gemm_k<true,false><<<dim3(8, 8), 256, 0, stream>>>(tmp_bf, Wka_bf, ka_bf, nullptr, 512, 512, 768);
    gemm_k<true,false><<<dim3(8, 8), 256, 0, stream>>>(tmp_bf, Wva_bf, va_bf, nullptr, 512, 512, 768);
    encattn_k<<<dim3(NB, 8), 256, 0, stream>>>(qa_bf, ka_bf, va_bf, o_bf);
    // h = h + o @ Wo_a
    gemm_k<false,true><<<dim3(8, 12), 256, 0, stream>>>(o_bf, Woa_bf, hbuf, hbuf, 512, 768, 512);
    // ffn: f = LN(h, ln2); fw = f@W1; act = glu(fw); h = h + act@W2
    ln_k<false,true><<<512, 256, 0, stream>>>(hbuf, nullptr, ln2_g, ln2_b, tmp_bf);
    gemm_k<false,false><<<dim3(8, 96), 256, 0, stream>>>(tmp_bf, W1_bf, fw, nullptr, 512, 6144, 768);
    glu_k<<<512*INNER/256, 256, 0, stream>>>(fw, act_bf);
    gemm_k<false,true><<<dim3(8, 12), 256, 0, stream>>>(act_bf, W2_bf, hbuf, hbuf, 512, 768, 3072);
    // slots = LN(h, lnf)
    ln_k<false,false><<<512, 256, 0, stream>>>(hbuf, nullptr, lnf_g, lnf_b, slots);
  }

  // ---- outputs: slots, then attn_map (transposed, normalized) ----
  hipMemcpyAsync(d_out, slots, (size_t)512*768*4, hipMemcpyDeviceToDevice, stream);
  attnout_k<<<NB*NTOK*NSLOT/256, 256, 0, stream>>>(attn_pre, rowsum, (float*)d_out + 512*768);
}

// Round 2
// 1531.690 us; speedup vs baseline: 2.4629x; 2.4629x over previous
//
#include <hip/hip_runtime.h>
#include <hip/hip_bf16.h>
#include <stdint.h>

typedef _Float16 f16;
typedef __attribute__((ext_vector_type(8))) _Float16 f16x8;
typedef __attribute__((ext_vector_type(4))) _Float16 f16x4;
typedef __attribute__((ext_vector_type(4))) float f32x4;

#define GLOBAL_AS __attribute__((address_space(1)))
#define LDS_AS __attribute__((address_space(3)))

#define D_DIM 768
#define NTOK 1024
#define NSLOT 16
#define NB 32
#define HDIM 512   // H*DH
#define INNER 3072
#define SCALE_D 0.03608439182435161f   // 768^-0.5
#define SCALE_H 0.125f                 // 64^-0.5

// ---------- MFMA GEMM: C[M,N] = A[M,K] @ Bt[N,K]^T (+ optional f32 residual) ----------
// 128x128 tile, BK=32, 256 threads (4 waves, 2x2 of 64x64), 16x16x32 f16 MFMA.
// M%128==0, N%128==0, K%32==0. OUT: 0=f32, 1=f16.
template<int OUT, bool RES>
__global__ __launch_bounds__(256) void mgemm_k(
    const f16* __restrict__ A,    // [M,K]
    const f16* __restrict__ Bt,   // [N,K]
    void* __restrict__ Cout,
    const float* __restrict__ Res,
    int M, int N, int K)
{
  __shared__ __align__(16) f16 As[128*32];
  __shared__ __align__(16) f16 Bs[128*32];
  const int tid = threadIdx.x;
  const int lane = tid & 63;
  const int wave = tid >> 6;
  const int m0 = blockIdx.x*128, n0 = blockIdx.y*128;
  const int wm = (wave>>1)*64, wn = (wave&1)*64;
  const int quad = lane>>4, l16 = lane&15;

  // staging: thread t loads 16B chunks; LDS dest = tid*16 bytes (wave-uniform base + lane*16)
  const int sr = tid>>2;           // 0..63
  const int sc = (tid&3)*8;        // k-offset in elements
  const f16* gA0 = A  + (size_t)(m0 + sr)*K + sc;
  const f16* gA1 = gA0 + (size_t)64*K;
  const f16* gB0 = Bt + (size_t)(n0 + sr)*K + sc;
  const f16* gB1 = gB0 + (size_t)64*K;
  LDS_AS void* lA0 = (LDS_AS void*)&As[(size_t)tid*8];
  LDS_AS void* lA1 = (LDS_AS void*)&As[(size_t)(256+tid)*8];
  LDS_AS void* lB0 = (LDS_AS void*)&Bs[(size_t)tid*8];
  LDS_AS void* lB1 = (LDS_AS void*)&Bs[(size_t)(256+tid)*8];

  const f16* fA = &As[(wm + l16)*32 + quad*8];
  const f16* fB = &Bs[(wn + l16)*32 + quad*8];

  f32x4 acc[4][4] = {};

  for (int k0 = 0; k0 < K; k0 += 32){
    __builtin_amdgcn_global_load_lds((const GLOBAL_AS void*)(gA0 + k0), lA0, 16, 0, 0);
    __builtin_amdgcn_global_load_lds((const GLOBAL_AS void*)(gA1 + k0), lA1, 16, 0, 0);
    __builtin_amdgcn_global_load_lds((const GLOBAL_AS void*)(gB0 + k0), lB0, 16, 0, 0);
    __builtin_amdgcn_global_load_lds((const GLOBAL_AS void*)(gB1 + k0), lB1, 16, 0, 0);
    __syncthreads();
    f16x8 a[4], b[4];
    #pragma unroll
    for (int t=0;t<4;++t) a[t] = *(const f16x8*)(fA + t*16*32);
    #pragma unroll
    for (int t=0;t<4;++t) b[t] = *(const f16x8*)(fB + t*16*32);
    #pragma unroll
    for (int mt=0;mt<4;++mt)
      #pragma unroll
      for (int nt=0;nt<4;++nt)
        acc[mt][nt] = __builtin_amdgcn_mfma_f32_16x16x32_f16(a[mt], b[nt], acc[mt][nt], 0, 0, 0);
    __syncthreads();
  }

  // epilogue: C/D layout col=lane&15, row=quad*4+reg
  #pragma unroll
  for (int mt=0;mt<4;++mt){
    #pragma unroll
    for (int nt=0;nt<4;++nt){
      int gm = m0 + wm + mt*16 + quad*4;
      int gn = n0 + wn + nt*16 + l16;
      #pragma unroll
      for (int r=0;r<4;++r){
        float c = acc[mt][nt][r];
        if (RES) c += Res[(size_t)(gm+r)*N + gn];
        if (OUT == 1) ((f16*)Cout)[(size_t)(gm+r)*N + gn] = (f16)c;
        else          ((float*)Cout)[(size_t)(gm+r)*N + gn] = c;
      }
    }
  }
}

// ---------- LayerNorm over rows of width 768 ----------
template<bool ADD, int OUT>   // OUT: 0=f32, 1=f16
__global__ __launch_bounds__(256) void ln_k(
    const float* __restrict__ X, const float* __restrict__ X2,
    const float* __restrict__ g, const float* __restrict__ bb,
    void* __restrict__ out)
{
  __shared__ float rs[256], rss[256];
  const int row = blockIdx.x, tid = threadIdx.x;
  const float* x = X + (size_t)row*D_DIM;
  float vals[3]; float s=0.f, ss=0.f;
  #pragma unroll
  for (int t=0;t<3;++t){
    int c = tid + t*256;
    float v = x[c];
    if (ADD) v += X2[(size_t)row*D_DIM + c];
    vals[t]=v; s+=v; ss+=v*v;
  }
  rs[tid]=s; rss[tid]=ss; __syncthreads();
  for (int off=128; off>0; off>>=1){
    if (tid<off){ rs[tid]+=rs[tid+off]; rss[tid]+=rss[tid+off]; }
    __syncthreads();
  }
  float mean = rs[0]*(1.0f/768.0f);
  float var  = rss[0]*(1.0f/768.0f) - mean*mean;
  float inv  = rsqrtf(var + 1e-5f);
  #pragma unroll
  for (int t=0;t<3;++t){
    int c = tid + t*256;
    float y = (vals[t]-mean)*inv*g[c] + bb[c];
    if (OUT==1) ((f16*)out)[(size_t)row*D_DIM + c] = (f16)y;
    else        ((float*)out)[(size_t)row*D_DIM + c] = y;
  }
}

// ---------- slots init ----------
__global__ __launch_bounds__(256) void slots_init_k(
    const float* __restrict__ noise, const float* __restrict__ mu,
    const float* __restrict__ ls, float* __restrict__ slots)
{
  int idx = blockIdx.x*256 + threadIdx.x;   // 512*768
  int d = idx % D_DIM;
  slots[idx] = mu[d] + expf(ls[d]) * noise[idx];
}

// ---------- dots + inverted softmax (over slot axis) + EPS + rowsum ----------
__global__ __launch_bounds__(256) void dots_k(
    const f16* __restrict__ Q,   // [32,16,768]
    const f16* __restrict__ Km,  // [32,1024,768]
    float* __restrict__ attn,    // [32,16,1024]
    float* __restrict__ rowsum)  // [512]
{
  __shared__ float qs[16][68];
  __shared__ float ks[64][68];
  __shared__ float ds[16][68];
  const int b = blockIdx.x, j0 = blockIdx.y*64;
  const int tid = threadIdx.x;
  const int ci = tid & 15;
  const int cj = (tid>>4)*4;
  float acc[4] = {0.f,0.f,0.f,0.f};
  for (int d0=0; d0<D_DIM; d0+=64){
    { // q tile 16x64
      int i = tid>>4, dd=(tid&15)*4;
      f16x4 u = *(const f16x4*)(Q + ((size_t)(b*NSLOT+i))*D_DIM + d0 + dd);
      float4 f = { (float)u.x, (float)u.y, (float)u.z, (float)u.w };
      *(float4*)&qs[i][dd] = f;
    }
    { // k tile 64x64
      int jj = tid>>2, base=(tid&3)*16;
      const f16* p = Km + ((size_t)(b*NTOK + j0 + jj))*D_DIM + d0 + base;
      #pragma unroll
      for (int t=0;t<4;++t){
        f16x4 u = *(const f16x4*)(p + t*4);
        float4 f = { (float)u.x, (float)u.y, (float)u.z, (float)u.w };
        *(float4*)&ks[jj][base + t*4] = f;
      }
    }
    __syncthreads();
    #pragma unroll 8
    for (int dd=0; dd<64; ++dd){
      float qv = qs[ci][dd];
      acc[0]+=qv*ks[cj+0][dd]; acc[1]+=qv*ks[cj+1][dd];
      acc[2]+=qv*ks[cj+2][dd]; acc[3]+=qv*ks[cj+3][dd];
    }
    __syncthreads();
  }
  #pragma unroll
  for (int t=0;t<4;++t) ds[ci][cj+t] = acc[t]*SCALE_D;
  __syncthreads();
  if (tid < 64){
    int jj = tid;
    float mx = -1e30f;
    #pragma unroll
    for (int i=0;i<16;++i) mx = fmaxf(mx, ds[i][jj]);
    float e[16]; float sm=0.f;
    #pragma unroll
    for (int i=0;i<16;++i){ e[i]=__expf(ds[i][jj]-mx); sm+=e[i]; }
    float inv = 1.0f/sm;
    #pragma unroll
    for (int i=0;i<16;++i){
      float a = e[i]*inv + 1e-8f;
      ds[i][jj] = a;
      attn[((size_t)b*NSLOT+i)*NTOK + j0 + jj] = a;
    }
  }
  __syncthreads();
  if (tid < 16){
    float s = 0.f;
    #pragma unroll 8
    for (int jj=0;jj<64;++jj) s += ds[tid][jj];
    atomicAdd(&rowsum[b*NSLOT + tid], s);
  }
}

// ---------- updates = (attn_pre @ V) / rowsum ----------
__global__ __launch_bounds__(256) void attnv_k(
    const float* __restrict__ attn,   // [32,16,1024]
    const float* __restrict__ rowsum, // [512]
    const f16* __restrict__ V,        // [32,1024,768]
    float* __restrict__ upd)          // [32,16,768]
{
  __shared__ float as_[16][68];
  __shared__ float vs[64][132];
  const int b = blockIdx.x, dbase = blockIdx.y*128;
  const int tid = threadIdx.x;
  const int ci = tid>>4;        // i
  const int cd = (tid&15)*8;    // d within 128
  float acc[8] = {};
  for (int j0=0; j0<NTOK; j0+=64){
    { // attn tile 16x64
      int i = tid>>4, jj=(tid&15)*4;
      float4 a4 = *(const float4*)&attn[((size_t)b*NSLOT+i)*NTOK + j0 + jj];
      *(float4*)&as_[i][jj] = a4;
    }
    { // V tile 64x128
      int jj = tid>>2, ds0=(tid&3)*32;
      const f16* p = V + ((size_t)(b*NTOK+j0+jj))*D_DIM + dbase + ds0;
      #pragma unroll
      for (int t=0;t<8;++t){
        f16x4 u = *(const f16x4*)(p + t*4);
        float4 f = { (float)u.x, (float)u.y, (float)u.z, (float)u.w };
        *(float4*)&vs[jj][ds0 + t*4] = f;
      }
    }
    __syncthreads();
    #pragma unroll 4
    for (int jj=0;jj<64;++jj){
      float av = as_[ci][jj];
      #pragma unroll
      for (int t=0;t<8;++t) acc[t] += av*vs[jj][cd+t];
    }
    __syncthreads();
  }
  float inv = 1.0f / rowsum[b*NSLOT + ci];
  #pragma unroll
  for (int t=0;t<8;++t)
    upd[((size_t)b*NSLOT+ci)*D_DIM + dbase + cd + t] = acc[t]*inv;
}

// ---------- encoder self-attention (tiny: 16x16 per (b,h)) ----------
__global__ __launch_bounds__(256) void encattn_k(
    const f16* __restrict__ QA, // [32,16,512]
    const f16* __restrict__ KA,
    const f16* __restrict__ VA,
    f16* __restrict__ O)        // [32,16,512]
{
  __shared__ float qs[16][68], ks[16][68], vs[16][68], ps[16][20];
  const int b = blockIdx.x, h = blockIdx.y;
  const int tid = threadIdx.x;
  {
    int i = tid>>4, dd=(tid&15)*4;
    size_t base = ((size_t)(b*NSLOT+i))*HDIM + h*64 + dd;
    f16x4 uq = *(const f16x4*)(QA + base);
    f16x4 uk = *(const f16x4*)(KA + base);
    f16x4 uv = *(const f16x4*)(VA + base);
    float4 fq = { (float)uq.x, (float)uq.y, (float)uq.z, (float)uq.w };
    float4 fk = { (float)uk.x, (float)uk.y, (float)uk.z, (float)uk.w };
    float4 fv = { (float)uv.x, (float)uv.y, (float)uv.z, (float)uv.w };
    *(float4*)&qs[i][dd]=fq; *(float4*)&ks[i][dd]=fk; *(float4*)&vs[i][dd]=fv;
  }
  __syncthreads();
  {
    int i = tid>>4, j = tid&15;
    float s=0.f;
    #pragma unroll 8
    for (int d=0; d<64; ++d) s += qs[i][d]*ks[j][d];
    ps[i][j] = s*SCALE_H;
  }
  __syncthreads();
  if (tid < 16){
    int i = tid;
    float mx=-1e30f;
    #pragma unroll
    for (int j=0;j<16;++j) mx = fmaxf(mx, ps[i][j]);
    float sm=0.f;
    #pragma unroll
    for (int j=0;j<16;++j){ float e=__expf(ps[i][j]-mx); ps[i][j]=e; sm+=e; }
    float inv=1.0f/sm;
    #pragma unroll
    for (int j=0;j<16;++j) ps[i][j]*=inv;
  }
  __syncthreads();
  {
    int i = tid>>4, dq=(tid&15)*4;
    float a0=0,a1=0,a2=0,a3=0;
    #pragma unroll
    for (int j=0;j<16;++j){
      float p = ps[i][j];
      a0+=p*vs[j][dq+0]; a1+=p*vs[j][dq+1]; a2+=p*vs[j][dq+2]; a3+=p*vs[j][dq+3];
    }
    size_t base = ((size_t)(b*NSLOT+i))*HDIM + h*64 + dq;
    O[base+0]=(f16)a0; O[base+1]=(f16)a1; O[base+2]=(f16)a2; O[base+3]=(f16)a3;
  }
}

// ---------- GLU activation: act = u * silu(g) ----------
__global__ __launch_bounds__(256) void glu_k(
    const float* __restrict__ fw, f16* __restrict__ act)
{
  int idx = blockIdx.x*256 + threadIdx.x;   // 512*3072
  int r = idx / INNER, c = idx % INNER;
  float u = fw[(size_t)r*(2*INNER) + c];
  float g = fw[(size_t)r*(2*INNER) + INNER + c];
  float sg = g / (1.0f + __expf(-g));
  act[idx] = (f16)(u*sg);
}

// ---------- f32 -> f16 transposed cast: out[C][R] = in[R][C] ----------
__global__ __launch_bounds__(256) void cast_t_k(
    const float* __restrict__ in, f16* __restrict__ out, int R, int C)
{
  __shared__ float t[32][33];
  int r0 = blockIdx.x*32, c0 = blockIdx.y*32;
  int tr = threadIdx.x & 31, g8 = threadIdx.x >> 5;
  #pragma unroll
  for (int s=0;s<4;++s){
    int r = g8*4 + s;
    t[r][tr] = in[(size_t)(r0+r)*C + c0+tr];
  }
  __syncthreads();
  #pragma unroll
  for (int s=0;s<4;++s){
    int c = g8*4+s;
    out[(size_t)(c0+c)*R + r0+tr] = (f16)t[tr][c];
  }
}

// ---------- attn_map output: out[b,j,i] = attn[b,i,j]/rowsum[b,i] ----------
__global__ __launch_bounds__(256) void attnout_k(
    const float* __restrict__ attn, const float* __restrict__ rowsum,
    float* __restrict__ out)
{
  int idx = blockIdx.x*256 + threadIdx.x;  // 32*1024*16
  int i = idx & 15;
  int j = (idx >> 4) & 1023;
  int b = idx >> 14;
  out[idx] = attn[((size_t)b*NSLOT+i)*NTOK + j] / rowsum[b*NSLOT + i];
}

extern "C" void kernel_launch(void* const* d_in, const int* in_sizes, int n_in,
                              void* d_out, int out_size, void* d_ws, size_t ws_size,
                              hipStream_t stream) {
  const float* x        = (const float*)d_in[0];
  const float* noise    = (const float*)d_in[1];
  const float* init_mu  = (const float*)d_in[2];
  const float* init_ls  = (const float*)d_in[3];
  const float* Wk       = (const float*)d_in[4];
  const float* Wv       = (const float*)d_in[5];
  const float* Wq       = (const float*)d_in[6];
  const float* ni_g     = (const float*)d_in[7];
  const float* ni_b     = (const float*)d_in[8];
  const float* ns_g     = (const float*)d_in[9];
  const float* ns_b     = (const float*)d_in[10];
  const float* nica_g   = (const float*)d_in[11];
  const float* nica_b   = (const float*)d_in[12];
  const float* ln1_g    = (const float*)d_in[13];
  const float* ln1_b    = (const float*)d_in[14];
  const float* Wq_a     = (const float*)d_in[15];
  const float* Wk_a     = (const float*)d_in[16];
  const float* Wv_a     = (const float*)d_in[17];
  const float* Wo_a     = (const float*)d_in[18];
  const float* ln2_g    = (const float*)d_in[19];
  const float* ln2_b    = (const float*)d_in[20];
  const float* W1       = (const float*)d_in[21];
  const float* W2       = (const float*)d_in[22];
  const float* lnf_g    = (const float*)d_in[23];
  const float* lnf_b    = (const float*)d_in[24];

  // ---- workspace layout ----
  char* w = (char*)d_ws;
  size_t off = 0;
  auto alloc = [&](size_t bytes)->char*{
    char* p = w + off; off += (bytes + 255) & ~(size_t)255; return p;
  };
  f16* xn_h = (f16*)alloc((size_t)NB*NTOK*D_DIM*2);
  f16* k_h  = (f16*)alloc((size_t)NB*NTOK*D_DIM*2);
  f16* v_h  = (f16*)alloc((size_t)NB*NTOK*D_DIM*2);
  f16* WkT  = (f16*)alloc(768*768*2);
  f16* WvT  = (f16*)alloc(768*768*2);
  f16* WqT  = (f16*)alloc(768*768*2);
  f16* WqaT = (f16*)alloc(768*512*2);
  f16* WkaT = (f16*)alloc(768*512*2);
  f16* WvaT = (f16*)alloc(768*512*2);
  f16* WoaT = (f16*)alloc(512*768*2);
  f16* W1T  = (f16*)alloc((size_t)768*6144*2);
  f16* W2T  = (f16*)alloc((size_t)3072*768*2);
  float* slots = (float*)alloc(512*768*4);
  float* hbuf  = (float*)alloc(512*768*4);
  float* upd   = (float*)alloc(512*768*4);
  f16* tmp_h = (f16*)alloc(512*768*2);
  f16* q_h   = (f16*)alloc(512*768*2);
  f16* qa_h  = (f16*)alloc(512*512*2);
  f16* ka_h  = (f16*)alloc(512*512*2);
  f16* va_h  = (f16*)alloc(512*512*2);
  f16* o_h   = (f16*)alloc(512*512*2);
  float* fw    = (float*)alloc((size_t)512*6144*4);
  f16* act_h = (f16*)alloc((size_t)512*3072*2);
  float* attn_pre = (float*)alloc((size_t)NB*NSLOT*NTOK*4);
  float* rowsum   = (float*)alloc(512*4);

  // ---- cast weights to f16, transposed (Bt[N][K] layout for mgemm) ----
  auto castT = [&](const float* src, f16* dst, int R, int C){
    cast_t_k<<<dim3(R/32, C/32), 256, 0, stream>>>(src, dst, R, C);
  };
  castT(Wk,   WkT,  768, 768);
  castT(Wv,   WvT,  768, 768);
  castT(Wq,   WqT,  768, 768);
  castT(Wq_a, WqaT, 768, 512);
  castT(Wk_a, WkaT, 768, 512);
  castT(Wv_a, WvaT, 768, 512);
  castT(Wo_a, WoaT, 512, 768);
  castT(W1,   W1T,  768, 6144);
  castT(W2,   W2T,  3072, 768);

  // ---- xn = LN(x); k = xn@Wk; v = xn@Wv ----
  ln_k<false,1><<<NB*NTOK, 256, 0, stream>>>(x, nullptr, ni_g, ni_b, xn_h);
  mgemm_k<1,false><<<dim3(NB*NTOK/128, 768/128), 256, 0, stream>>>(xn_h, WkT, k_h, nullptr, NB*NTOK, 768, 768);
  mgemm_k<1,false><<<dim3(NB*NTOK/128, 768/128), 256, 0, stream>>>(xn_h, WvT, v_h, nullptr, NB*NTOK, 768, 768);

  // ---- slots init ----
  slots_init_k<<<512*768/256, 256, 0, stream>>>(noise, init_mu, init_ls, slots);

  // ---- 4 iterations ----
  for (int it=0; it<4; ++it){
    // q = LN(slots, ns) @ Wq
    ln_k<false,1><<<512, 256, 0, stream>>>(slots, nullptr, ns_g, ns_b, tmp_h);
    mgemm_k<1,false><<<dim3(4, 6), 256, 0, stream>>>(tmp_h, WqT, q_h, nullptr, 512, 768, 768);
    // dots + inverted softmax
    hipMemsetAsync(rowsum, 0, 512*4, stream);
    dots_k<<<dim3(NB, NTOK/64), 256, 0, stream>>>(q_h, k_h, attn_pre, rowsum);
    // updates = (attn/rowsum) @ v
    attnv_k<<<dim3(NB, D_DIM/128), 256, 0, stream>>>(attn_pre, rowsum, v_h, upd);
    // h = LN(slots + updates, nica)
    ln_k<true,0><<<512, 256, 0, stream>>>(slots, upd, nica_g, nica_b, hbuf);
    // encoder: a = LN(h, ln1); qa/ka/va
    ln_k<false,1><<<512, 256, 0, stream>>>(hbuf, nullptr, ln1_g, ln1_b, tmp_h);
    mgemm_k<1,false><<<dim3(4, 4), 256, 0, stream>>>(tmp_h, WqaT, qa_h, nullptr, 512, 512, 768);
    mgemm_k<1,false><<<dim3(4, 4), 256, 0, stream>>>(tmp_h, WkaT, ka_h, nullptr, 512, 512, 768);
    mgemm_k<1,false><<<dim3(4, 4), 256, 0, stream>>>(tmp_h, WvaT, va_h, nullptr, 512, 512, 768);
    encattn_k<<<dim3(NB, 8), 256, 0, stream>>>(qa_h, ka_h, va_h, o_h);
    // h = h + o @ Wo_a
    mgemm_k<0,true><<<dim3(4, 6), 256, 0, stream>>>(o_h, WoaT, hbuf, hbuf, 512, 768, 512);
    // ffn: f = LN(h, ln2); fw = f@W1; act = glu(fw); h = h + act@W2
    ln_k<false,1><<<512, 256, 0, stream>>>(hbuf, nullptr, ln2_g, ln2_b, tmp_h);
    mgemm_k<0,false><<<dim3(4, 48), 256, 0, stream>>>(tmp_h, W1T, fw, nullptr, 512, 6144, 768);
    glu_k<<<512*INNER/256, 256, 0, stream>>>(fw, act_h);
    mgemm_k<0,true><<<dim3(4, 6), 256, 0, stream>>>(act_h, W2T, hbuf, hbuf, 512, 768, 3072);
    // slots = LN(h, lnf)
    ln_k<false,0><<<512, 256, 0, stream>>>(hbuf, nullptr, lnf_g, lnf_b, slots);
  }

  // ---- outputs: slots, then attn_map (transposed, normalized) ----
  hipMemcpyAsync(d_out, slots, (size_t)512*768*4, hipMemcpyDeviceToDevice, stream);
  attnout_k<<<NB*NTOK*NSLOT/256, 256, 0, stream>>>(attn_pre, rowsum, (float*)d_out + 512*768);
}

// Round 3
// 983.713 us; speedup vs baseline: 3.8349x; 1.5571x over previous
//
#include <hip/hip_runtime.h>
#include <hip/hip_bf16.h>
#include <stdint.h>

typedef _Float16 f16;
typedef __attribute__((ext_vector_type(8))) _Float16 f16x8;
typedef __attribute__((ext_vector_type(4))) _Float16 f16x4;
typedef __attribute__((ext_vector_type(4))) float f32x4;

#define GLOBAL_AS __attribute__((address_space(1)))
#define LDS_AS __attribute__((address_space(3)))

#define D_DIM 768
#define NTOK 1024
#define NSLOT 16
#define NB 32
#define HDIM 512   // H*DH
#define INNER 3072
#define SCALE_D 0.03608439182435161f   // 768^-0.5
#define SCALE_H 0.125f                 // 64^-0.5

// ---------- MFMA GEMM 128x128 (for the one big M=32768 GEMM) ----------
// C[M,N](f16) = A[M,K] @ Bt[N,K]^T. BK=32, 256 thr, 4 waves 2x2 of 64x64.
__global__ __launch_bounds__(256) void mgemm128_k(
    const f16* __restrict__ A, const f16* __restrict__ Bt,
    f16* __restrict__ Cout, int M, int N, int K)
{
  __shared__ __align__(16) f16 As[128*32];
  __shared__ __align__(16) f16 Bs[128*32];
  const int tid = threadIdx.x;
  const int lane = tid & 63;
  const int wave = tid >> 6;
  const int m0 = blockIdx.x*128, n0 = blockIdx.y*128;
  const int wm = (wave>>1)*64, wn = (wave&1)*64;
  const int quad = lane>>4, l16 = lane&15;

  const int sr = tid>>2;           // 0..63
  const int sc = (tid&3)*8;
  const f16* gA0 = A  + (size_t)(m0 + sr)*K + sc;
  const f16* gA1 = gA0 + (size_t)64*K;
  const f16* gB0 = Bt + (size_t)(n0 + sr)*K + sc;
  const f16* gB1 = gB0 + (size_t)64*K;
  LDS_AS void* lA0 = (LDS_AS void*)&As[(size_t)tid*8];
  LDS_AS void* lA1 = (LDS_AS void*)&As[(size_t)(256+tid)*8];
  LDS_AS void* lB0 = (LDS_AS void*)&Bs[(size_t)tid*8];
  LDS_AS void* lB1 = (LDS_AS void*)&Bs[(size_t)(256+tid)*8];

  const f16* fA = &As[(wm + l16)*32 + quad*8];
  const f16* fB = &Bs[(wn + l16)*32 + quad*8];

  f32x4 acc[4][4] = {};

  for (int k0 = 0; k0 < K; k0 += 32){
    __builtin_amdgcn_global_load_lds((const GLOBAL_AS void*)(gA0 + k0), lA0, 16, 0, 0);
    __builtin_amdgcn_global_load_lds((const GLOBAL_AS void*)(gA1 + k0), lA1, 16, 0, 0);
    __builtin_amdgcn_global_load_lds((const GLOBAL_AS void*)(gB0 + k0), lB0, 16, 0, 0);
    __builtin_amdgcn_global_load_lds((const GLOBAL_AS void*)(gB1 + k0), lB1, 16, 0, 0);
    __syncthreads();
    f16x8 a[4], b[4];
    #pragma unroll
    for (int t=0;t<4;++t) a[t] = *(const f16x8*)(fA + t*16*32);
    #pragma unroll
    for (int t=0;t<4;++t) b[t] = *(const f16x8*)(fB + t*16*32);
    #pragma unroll
    for (int mt=0;mt<4;++mt)
      #pragma unroll
      for (int nt=0;nt<4;++nt)
        acc[mt][nt] = __builtin_amdgcn_mfma_f32_16x16x32_f16(a[mt], b[nt], acc[mt][nt], 0, 0, 0);
    __syncthreads();
  }
  #pragma unroll
  for (int mt=0;mt<4;++mt){
    #pragma unroll
    for (int nt=0;nt<4;++nt){
      int gm = m0 + wm + mt*16 + quad*4;
      int gn = n0 + wn + nt*16 + l16;
      #pragma unroll
      for (int r=0;r<4;++r)
        Cout[(size_t)(gm+r)*N + gn] = (f16)acc[mt][nt][r];
    }
  }
}

// ---------- MFMA GEMM 64x64, BK=128 (4 conflict-free 32-k panels), split-K ----------
// OUT: 0 = f32 store, 1 = f16 store, 2 = f32 atomicAdd.
// grid (M/64, N/64, S); Kc = K/S, Kc % 128 == 0.
template<int OUT>
__global__ __launch_bounds__(256) void mgemm64_k(
    const f16* __restrict__ A, const f16* __restrict__ Bt,
    void* __restrict__ Cout, int M, int N, int K, int Kc)
{
  __shared__ __align__(16) f16 As[64*128];
  __shared__ __align__(16) f16 Bs[64*128];
  const int tid = threadIdx.x;
  const int lane = tid & 63;
  const int wave = tid >> 6;
  const int m0 = blockIdx.x*64, n0 = blockIdx.y*64;
  const int kbeg = blockIdx.z * Kc;
  const int wm = (wave>>1)*32, wn = (wave&1)*32;
  const int quad = lane>>4, l16 = lane&15;

  const int sr = tid>>2;        // 0..63
  const int sc = (tid&3)*8;     // k offset within panel
  const f16* gA = A  + (size_t)(m0+sr)*K + kbeg + sc;
  const f16* gB = Bt + (size_t)(n0+sr)*K + kbeg + sc;
  LDS_AS f16* lA = (LDS_AS f16*)&As[(size_t)tid*8];
  LDS_AS f16* lB = (LDS_AS f16*)&Bs[(size_t)tid*8];

  const f16* fA0 = &As[(wm + l16)*32 + quad*8];
  const f16* fB0 = &Bs[(wn + l16)*32 + quad*8];

  f32x4 acc[2][2] = {};

  for (int k0 = 0; k0 < Kc; k0 += 128){
    #pragma unroll
    for (int p=0;p<4;++p){
      __builtin_amdgcn_global_load_lds((const GLOBAL_AS void*)(gA + k0 + p*32),
                                       (LDS_AS void*)(lA + (size_t)p*2048), 16, 0, 0);
      __builtin_amdgcn_global_load_lds((const GLOBAL_AS void*)(gB + k0 + p*32),
                                       (LDS_AS void*)(lB + (size_t)p*2048), 16, 0, 0);
    }
    __syncthreads();
    #pragma unroll
    for (int p=0;p<4;++p){
      f16x8 a0 = *(const f16x8*)(fA0 + p*2048);
      f16x8 a1 = *(const f16x8*)(fA0 + p*2048 + 16*32);
      f16x8 b0 = *(const f16x8*)(fB0 + p*2048);
      f16x8 b1 = *(const f16x8*)(fB0 + p*2048 + 16*32);
      acc[0][0] = __builtin_amdgcn_mfma_f32_16x16x32_f16(a0,b0,acc[0][0],0,0,0);
      acc[0][1] = __builtin_amdgcn_mfma_f32_16x16x32_f16(a0,b1,acc[0][1],0,0,0);
      acc[1][0] = __builtin_amdgcn_mfma_f32_16x16x32_f16(a1,b0,acc[1][0],0,0,0);
      acc[1][1] = __builtin_amdgcn_mfma_f32_16x16x32_f16(a1,b1,acc[1][1],0,0,0);
    }
    __syncthreads();
  }
  #pragma unroll
  for (int mt=0;mt<2;++mt){
    #pragma unroll
    for (int nt=0;nt<2;++nt){
      int gm = m0 + wm + mt*16 + quad*4;
      int gn = n0 + wn + nt*16 + l16;
      #pragma unroll
      for (int r=0;r<4;++r){
        float c = acc[mt][nt][r];
        size_t idx = (size_t)(gm+r)*N + gn;
        if (OUT==0)      ((float*)Cout)[idx] = c;
        else if (OUT==1) ((f16*)Cout)[idx] = (f16)c;
        else             atomicAdd(&((float*)Cout)[idx], c);
      }
    }
  }
}

// ---------- LayerNorm over rows of width 768 ----------
template<bool ADD, int OUT>   // OUT: 0=f32, 1=f16
__global__ __launch_bounds__(256) void ln_k(
    const float* __restrict__ X, const float* __restrict__ X2,
    const float* __restrict__ g, const float* __restrict__ bb,
    void* __restrict__ out)
{
  __shared__ float rs[256], rss[256];
  const int row = blockIdx.x, tid = threadIdx.x;
  const float* x = X + (size_t)row*D_DIM;
  float vals[3]; float s=0.f, ss=0.f;
  #pragma unroll
  for (int t=0;t<3;++t){
    int c = tid + t*256;
    float v = x[c];
    if (ADD) v += X2[(size_t)row*D_DIM + c];
    vals[t]=v; s+=v; ss+=v*v;
  }
  rs[tid]=s; rss[tid]=ss; __syncthreads();
  for (int off=128; off>0; off>>=1){
    if (tid<off){ rs[tid]+=rs[tid+off]; rss[tid]+=rss[tid+off]; }
    __syncthreads();
  }
  float mean = rs[0]*(1.0f/768.0f);
  float var  = rss[0]*(1.0f/768.0f) - mean*mean;
  float inv  = rsqrtf(var + 1e-5f);
  #pragma unroll
  for (int t=0;t<3;++t){
    int c = tid + t*256;
    float y = (vals[t]-mean)*inv*g[c] + bb[c];
    if (OUT==1) ((f16*)out)[(size_t)row*D_DIM + c] = (f16)y;
    else        ((float*)out)[(size_t)row*D_DIM + c] = y;
  }
}

// ---------- fused double LayerNorm: y1 = LN(x[+x2], g1,b1) -> out1 (f32);
//            y2 = LN(y1, g2,b2) -> out2 (f16) ----------
template<bool ADD>
__global__ __launch_bounds__(256) void lnln_k(
    const float* __restrict__ X, const float* __restrict__ X2,
    const float* __restrict__ g1, const float* __restrict__ b1,
    const float* __restrict__ g2, const float* __restrict__ b2,
    float* __restrict__ out1, f16* __restrict__ out2)
{
  __shared__ float rs[256], rss[256];
  const int row = blockIdx.x, tid = threadIdx.x;
  const float* x = X + (size_t)row*D_DIM;
  float vals[3]; float s=0.f, ss=0.f;
  #pragma unroll
  for (int t=0;t<3;++t){
    int c = tid + t*256;
    float v = x[c];
    if (ADD) v += X2[(size_t)row*D_DIM + c];
    vals[t]=v; s+=v; ss+=v*v;
  }
  rs[tid]=s; rss[tid]=ss; __syncthreads();
  for (int off=128; off>0; off>>=1){
    if (tid<off){ rs[tid]+=rs[tid+off]; rss[tid]+=rss[tid+off]; }
    __syncthreads();
  }
  float mean = rs[0]*(1.0f/768.0f);
  float var  = rss[0]*(1.0f/768.0f) - mean*mean;
  float inv  = rsqrtf(var + 1e-5f);
  float y[3]; float s2=0.f, ss2=0.f;
  #pragma unroll
  for (int t=0;t<3;++t){
    int c = tid + t*256;
    float yy = (vals[t]-mean)*inv*g1[c] + b1[c];
    y[t]=yy; s2+=yy; ss2+=yy*yy;
    out1[(size_t)row*D_DIM + c] = yy;
  }
  __syncthreads();
  rs[tid]=s2; rss[tid]=ss2; __syncthreads();
  for (int off=128; off>0; off>>=1){
    if (tid<off){ rs[tid]+=rs[tid+off]; rss[tid]+=rss[tid+off]; }
    __syncthreads();
  }
  float mean2 = rs[0]*(1.0f/768.0f);
  float var2  = rss[0]*(1.0f/768.0f) - mean2*mean2;
  float inv2  = rsqrtf(var2 + 1e-5f);
  #pragma unroll
  for (int t=0;t<3;++t){
    int c = tid + t*256;
    out2[(size_t)row*D_DIM + c] = (f16)((y[t]-mean2)*inv2*g2[c] + b2[c]);
  }
}

// ---------- slots init ----------
__global__ __launch_bounds__(256) void slots_init_k(
    const float* __restrict__ noise, const float* __restrict__ mu,
    const float* __restrict__ ls, float* __restrict__ slots)
{
  int idx = blockIdx.x*256 + threadIdx.x;   // 512*768
  int d = idx % D_DIM;
  slots[idx] = mu[d] + expf(ls[d]) * noise[idx];
}

// ---------- dots + inverted softmax (over slot axis) + EPS + rowsum ----------
// Q is f32 (atomic split-K output). Km has row stride KSTR (fused kv).
__global__ __launch_bounds__(256) void dots_k(
    const float* __restrict__ Q,  // [32,16,768] f32
    const f16* __restrict__ Km,   // [32,1024,KSTR] f16
    int KSTR,
    float* __restrict__ attn,     // [32,16,1024]
    float* __restrict__ rowsum)   // [512]
{
  __shared__ float qs[16][68];
  __shared__ float ks[64][68];
  __shared__ float ds[16][68];
  const int b = blockIdx.x, j0 = blockIdx.y*64;
  const int tid = threadIdx.x;
  const int ci = tid & 15;
  const int cj = (tid>>4)*4;
  float acc[4] = {0.f,0.f,0.f,0.f};
  for (int d0=0; d0<D_DIM; d0+=64){
    { // q tile 16x64 (f32)
      int i = tid>>4, dd=(tid&15)*4;
      float4 f = *(const float4*)(Q + ((size_t)(b*NSLOT+i))*D_DIM + d0 + dd);
      *(float4*)&qs[i][dd] = f;
    }
    { // k tile 64x64
      int jj = tid>>2, base=(tid&3)*16;
      const f16* p = Km + ((size_t)(b*NTOK + j0 + jj))*KSTR + d0 + base;
      #pragma unroll
      for (int t=0;t<4;++t){
        f16x4 u = *(const f16x4*)(p + t*4);
        float4 f = { (float)u.x, (float)u.y, (float)u.z, (float)u.w };
        *(float4*)&ks[jj][base + t*4] = f;
      }
    }
    __syncthreads();
    #pragma unroll 8
    for (int dd=0; dd<64; ++dd){
      float qv = qs[ci][dd];
      acc[0]+=qv*ks[cj+0][dd]; acc[1]+=qv*ks[cj+1][dd];
      acc[2]+=qv*ks[cj+2][dd]; acc[3]+=qv*ks[cj+3][dd];
    }
    __syncthreads();
  }
  #pragma unroll
  for (int t=0;t<4;++t) ds[ci][cj+t] = acc[t]*SCALE_D;
  __syncthreads();
  if (tid < 64){
    int jj = tid;
    float mx = -1e30f;
    #pragma unroll
    for (int i=0;i<16;++i) mx = fmaxf(mx, ds[i][jj]);
    float e[16]; float sm=0.f;
    #pragma unroll
    for (int i=0;i<16;++i){ e[i]=__expf(ds[i][jj]-mx); sm+=e[i]; }
    float inv = 1.0f/sm;
    #pragma unroll
    for (int i=0;i<16;++i){
      float a = e[i]*inv + 1e-8f;
      ds[i][jj] = a;
      attn[((size_t)b*NSLOT+i)*NTOK + j0 + jj] = a;
    }
  }
  __syncthreads();
  if (tid < 16){
    float s = 0.f;
    #pragma unroll 8
    for (int jj=0;jj<64;++jj) s += ds[tid][jj];
    atomicAdd(&rowsum[b*NSLOT + tid], s);
  }
}

// ---------- updates = (attn_pre @ V) / rowsum ----------
__global__ __launch_bounds__(256) void attnv_k(
    const float* __restrict__ attn,   // [32,16,1024]
    const float* __restrict__ rowsum, // [512]
    const f16* __restrict__ V,        // [32,1024,KSTR]
    int KSTR,
    float* __restrict__ upd)          // [32,16,768]
{
  __shared__ float as_[16][68];
  __shared__ float vs[64][132];
  const int b = blockIdx.x, dbase = blockIdx.y*128;
  const int tid = threadIdx.x;
  const int ci = tid>>4;        // i
  const int cd = (tid&15)*8;    // d within 128
  float acc[8] = {};
  for (int j0=0; j0<NTOK; j0+=64){
    { // attn tile 16x64
      int i = tid>>4, jj=(tid&15)*4;
      float4 a4 = *(const float4*)&attn[((size_t)b*NSLOT+i)*NTOK + j0 + jj];
      *(float4*)&as_[i][jj] = a4;
    }
    { // V tile 64x128
      int jj = tid>>2, ds0=(tid&3)*32;
      const f16* p = V + ((size_t)(b*NTOK+j0+jj))*KSTR + dbase + ds0;
      #pragma unroll
      for (int t=0;t<8;++t){
        f16x4 u = *(const f16x4*)(p + t*4);
        float4 f = { (float)u.x, (float)u.y, (float)u.z, (float)u.w };
        *(float4*)&vs[jj][ds0 + t*4] = f;
      }
    }
    __syncthreads();
    #pragma unroll 4
    for (int jj=0;jj<64;++jj){
      float av = as_[ci][jj];
      #pragma unroll
      for (int t=0;t<8;++t) acc[t] += av*vs[jj][cd+t];
    }
    __syncthreads();
  }
  float inv = 1.0f / rowsum[b*NSLOT + ci];
  #pragma unroll
  for (int t=0;t<8;++t)
    upd[((size_t)b*NSLOT+ci)*D_DIM + dbase + cd + t] = acc[t]*inv;
}

// ---------- encoder self-attention (tiny: 16x16 per (b,h)) ----------
// QA/KA/VA point into the fused qkv buffer; row stride QSTR.
__global__ __launch_bounds__(256) void encattn_k(
    const f16* __restrict__ QA, const f16* __restrict__ KA,
    const f16* __restrict__ VA, int QSTR,
    f16* __restrict__ O)        // [32,16,512] f16
{
  __shared__ float qs[16][68], ks[16][68], vs[16][68], ps[16][20];
  const int b = blockIdx.x, h = blockIdx.y;
  const int tid = threadIdx.x;
  {
    int i = tid>>4, dd=(tid&15)*4;
    size_t base = ((size_t)(b*NSLOT+i))*QSTR + h*64 + dd;
    f16x4 uq = *(const f16x4*)(QA + base);
    f16x4 uk = *(const f16x4*)(KA + base);
    f16x4 uv = *(const f16x4*)(VA + base);
    float4 fq = { (float)uq.x, (float)uq.y, (float)uq.z, (float)uq.w };
    float4 fk = { (float)uk.x, (float)uk.y, (float)uk.z, (float)uk.w };
    float4 fv = { (float)uv.x, (float)uv.y, (float)uv.z, (float)uv.w };
    *(float4*)&qs[i][dd]=fq; *(float4*)&ks[i][dd]=fk; *(float4*)&vs[i][dd]=fv;
  }
  __syncthreads();
  {
    int i = tid>>4, j = tid&15;
    float s=0.f;
    #pragma unroll 8
    for (int d=0; d<64; ++d) s += qs[i][d]*ks[j][d];
    ps[i][j] = s*SCALE_H;
  }
  __syncthreads();
  if (tid < 16){
    int i = tid;
    float mx=-1e30f;
    #pragma unroll
    for (int j=0;j<16;++j) mx = fmaxf(mx, ps[i][j]);
    float sm=0.f;
    #pragma unroll
    for (int j=0;j<16;++j){ float e=__expf(ps[i][j]-mx); ps[i][j]=e; sm+=e; }
    float inv=1.0f/sm;
    #pragma unroll
    for (int j=0;j<16;++j) ps[i][j]*=inv;
  }
  __syncthreads();
  {
    int i = tid>>4, dq=(tid&15)*4;
    float a0=0,a1=0,a2=0,a3=0;
    #pragma unroll
    for (int j=0;j<16;++j){
      float p = ps[i][j];
      a0+=p*vs[j][dq+0]; a1+=p*vs[j][dq+1]; a2+=p*vs[j][dq+2]; a3+=p*vs[j][dq+3];
    }
    size_t base = ((size_t)(b*NSLOT+i))*HDIM + h*64 + dq;
    O[base+0]=(f16)a0; O[base+1]=(f16)a1; O[base+2]=(f16)a2; O[base+3]=(f16)a3;
  }
}

// ---------- GLU activation: act = u * silu(g), f16 in/out ----------
__global__ __launch_bounds__(256) void glu_k(
    const f16* __restrict__ fw, f16* __restrict__ act)
{
  int idx = blockIdx.x*256 + threadIdx.x;   // 512*3072
  int r = idx / INNER, c = idx % INNER;
  float u = (float)fw[(size_t)r*(2*INNER) + c];
  float g = (float)fw[(size_t)r*(2*INNER) + INNER + c];
  float sg = g / (1.0f + __expf(-g));
  act[idx] = (f16)(u*sg);
}

// ---------- f32 -> f16 transposed cast: out[C][R] = in[R][C] ----------
__global__ __launch_bounds__(256) void cast_t_k(
    const float* __restrict__ in, f16* __restrict__ out, int R, int C)
{
  __shared__ float t[32][33];
  int r0 = blockIdx.x*32, c0 = blockIdx.y*32;
  int tr = threadIdx.x & 31, g8 = threadIdx.x >> 5;
  #pragma unroll
  for (int s=0;s<4;++s){
    int r = g8*4 + s;
    t[r][tr] = in[(size_t)(r0+r)*C + c0+tr];
  }
  __syncthreads();
  #pragma unroll
  for (int s=0;s<4;++s){
    int c = g8*4+s;
    out[(size_t)(c0+c)*R + r0+tr] = (f16)t[tr][c];
  }
}

// ---------- attn_map output: out[b,j,i] = attn[b,i,j]/rowsum[b,i] ----------
__global__ __launch_bounds__(256) void attnout_k(
    const float* __restrict__ attn, const float* __restrict__ rowsum,
    float* __restrict__ out)
{
  int idx = blockIdx.x*256 + threadIdx.x;  // 32*1024*16
  int i = idx & 15;
  int j = (idx >> 4) & 1023;
  int b = idx >> 14;
  out[idx] = attn[((size_t)b*NSLOT+i)*NTOK + j] / rowsum[b*NSLOT + i];
}

extern "C" void kernel_launch(void* const* d_in, const int* in_sizes, int n_in,
                              void* d_out, int out_size, void* d_ws, size_t ws_size,
                              hipStream_t stream) {
  const float* x        = (const float*)d_in[0];
  const float* noise    = (const float*)d_in[1];
  const float* init_mu  = (const float*)d_in[2];
  const float* init_ls  = (const float*)d_in[3];
  const float* Wk       = (const float*)d_in[4];
  const float* Wv       = (const float*)d_in[5];
  const float* Wq       = (const float*)d_in[6];
  const float* ni_g     = (const float*)d_in[7];
  const float* ni_b     = (const float*)d_in[8];
  const float* ns_g     = (const float*)d_in[9];
  const float* ns_b     = (const float*)d_in[10];
  const float* nica_g   = (const float*)d_in[11];
  const float* nica_b   = (const float*)d_in[12];
  const float* ln1_g    = (const float*)d_in[13];
  const float* ln1_b    = (const float*)d_in[14];
  const float* Wq_a     = (const float*)d_in[15];
  const float* Wk_a     = (const float*)d_in[16];
  const float* Wv_a     = (const float*)d_in[17];
  const float* Wo_a     = (const float*)d_in[18];
  const float* ln2_g    = (const float*)d_in[19];
  const float* ln2_b    = (const float*)d_in[20];
  const float* W1       = (const float*)d_in[21];
  const float* W2       = (const float*)d_in[22];
  const float* lnf_g    = (const float*)d_in[23];
  const float* lnf_b    = (const float*)d_in[24];

  // ---- workspace layout ----
  char* w = (char*)d_ws;
  size_t off = 0;
  auto alloc = [&](size_t bytes)->char*{
    char* p = w + off; off += (bytes + 255) & ~(size_t)255; return p;
  };
  f16* xn_h  = (f16*)alloc((size_t)NB*NTOK*D_DIM*2);      // 48 MB
  f16* kv_h  = (f16*)alloc((size_t)NB*NTOK*1536*2);       // 96 MB (k | v fused)
  f16* WkvT  = (f16*)alloc((size_t)1536*768*2);           // [1536][768]
  f16* WqT   = (f16*)alloc((size_t)768*768*2);
  f16* WqkvT = (f16*)alloc((size_t)1536*768*2);           // [qa|ka|va][768]
  f16* WoaT  = (f16*)alloc((size_t)768*512*2);            // [768][512]
  f16* W1T   = (f16*)alloc((size_t)6144*768*2);
  f16* W2T   = (f16*)alloc((size_t)768*3072*2);
  float* slots = (float*)alloc(512*768*4);
  float* hbuf  = (float*)alloc(512*768*4);
  float* upd   = (float*)alloc(512*768*4);
  f16* tmp_h  = (f16*)alloc(512*768*2);
  f16* tmp2_h = (f16*)alloc(512*768*2);   // LN(slots, ns) for q proj
  f16* qkv_h  = (f16*)alloc((size_t)512*1536*2);
  f16* o_h    = (f16*)alloc(512*512*2);
  f16* fw_h   = (f16*)alloc((size_t)512*6144*2);
  f16* act_h  = (f16*)alloc((size_t)512*3072*2);
  float* attn_pre = (float*)alloc((size_t)NB*NSLOT*NTOK*4);
  float* q_f   = (float*)alloc(512*768*4);   // 1572864 B (256-aligned)
  float* rowsum = (float*)alloc(512*4);       // contiguous after q_f

  // ---- cast weights to f16, transposed ([N][K] for gemm Bt) ----
  auto castT = [&](const float* src, f16* dst, int R, int C){
    cast_t_k<<<dim3(R/32, C/32), 256, 0, stream>>>(src, dst, R, C);
  };
  castT(Wk,   WkvT,            768, 768);
  castT(Wv,   WkvT + 768*768,  768, 768);
  castT(Wq,   WqT,             768, 768);
  castT(Wq_a, WqkvT,             768, 512);
  castT(Wk_a, WqkvT + 512*768,   768, 512);
  castT(Wv_a, WqkvT + 1024*768,  768, 512);
  castT(Wo_a, WoaT,            512, 768);
  castT(W1,   W1T,             768, 6144);
  castT(W2,   W2T,             3072, 768);

  // ---- xn = LN(x); kv = xn @ [Wk|Wv] (fused) ----
  ln_k<false,1><<<NB*NTOK, 256, 0, stream>>>(x, nullptr, ni_g, ni_b, xn_h);
  mgemm128_k<<<dim3(NB*NTOK/128, 1536/128), 256, 0, stream>>>(xn_h, WkvT, kv_h, NB*NTOK, 1536, 768);

  // ---- slots init + first LN(slots, ns) ----
  slots_init_k<<<512*768/256, 256, 0, stream>>>(noise, init_mu, init_ls, slots);
  ln_k<false,1><<<512, 256, 0, stream>>>(slots, nullptr, ns_g, ns_b, tmp2_h);

  // ---- 4 iterations ----
  for (int it=0; it<4; ++it){
    // zero q_f (+rowsum, contiguous)
    hipMemsetAsync(q_f, 0, 512*768*4 + 512*4, stream);
    // q = LN(slots,ns) @ Wq  (split-K=2, atomic f32)
    mgemm64_k<2><<<dim3(8, 12, 2), 256, 0, stream>>>(tmp2_h, WqT, q_f, 512, 768, 768, 384);
    // dots + inverted softmax
    dots_k<<<dim3(NB, NTOK/64), 256, 0, stream>>>(q_f, kv_h, 1536, attn_pre, rowsum);
    // updates = (attn/rowsum) @ v
    attnv_k<<<dim3(NB, D_DIM/128), 256, 0, stream>>>(attn_pre, rowsum, kv_h + 768, 1536, upd);
    // h = LN(slots+upd, nica) -> hbuf ; a = LN(h, ln1) -> tmp_h
    lnln_k<true><<<512, 256, 0, stream>>>(slots, upd, nica_g, nica_b, ln1_g, ln1_b, hbuf, tmp_h);
    // qkv = a @ [Wq_a|Wk_a|Wv_a]
    mgemm64_k<1><<<dim3(8, 24, 1), 256, 0, stream>>>(tmp_h, WqkvT, qkv_h, 512, 1536, 768, 768);
    encattn_k<<<dim3(NB, 8), 256, 0, stream>>>(qkv_h, qkv_h + 512, qkv_h + 1024, 1536, o_h);
    // h += o @ Wo_a  (split-K=2, atomic into hbuf)
    mgemm64_k<2><<<dim3(8, 12, 2), 256, 0, stream>>>(o_h, WoaT, hbuf, 512, 768, 512, 256);
    // f = LN(h, ln2)
    ln_k<false,1><<<512, 256, 0, stream>>>(hbuf, nullptr, ln2_g, ln2_b, tmp_h);
    // fw = f @ W1 (f16 out)
    mgemm64_k<1><<<dim3(8, 96, 1), 256, 0, stream>>>(tmp_h, W1T, fw_h, 512, 6144, 768, 768);
    glu_k<<<512*INNER/256, 256, 0, stream>>>(fw_h, act_h);
    // h += act @ W2  (split-K=4, atomic into hbuf)
    mgemm64_k<2><<<dim3(8, 12, 4), 256, 0, stream>>>(act_h, W2T, hbuf, 512, 768, 3072, 768);
    // slots = LN(h, lnf) ; tmp2 = LN(slots, ns) for next iter's q proj
    lnln_k<false><<<512, 256, 0, stream>>>(hbuf, nullptr, lnf_g, lnf_b, ns_g, ns_b, slots, tmp2_h);
  }

  // ---- outputs: slots, then attn_map (transposed, normalized) ----
  hipMemcpyAsync(d_out, slots, (size_t)512*768*4, hipMemcpyDeviceToDevice, stream);
  attnout_k<<<NB*NTOK*NSLOT/256, 256, 0, stream>>>(attn_pre, rowsum, (float*)d_out + 512*768);
}

// Round 4
// 919.296 us; speedup vs baseline: 4.1036x; 1.0701x over previous
//
#include <hip/hip_runtime.h>
#include <hip/hip_bf16.h>
#include <stdint.h>

typedef _Float16 f16;
typedef __attribute__((ext_vector_type(8))) _Float16 f16x8;
typedef __attribute__((ext_vector_type(4))) _Float16 f16x4;
typedef __attribute__((ext_vector_type(4))) float f32x4;

#define GLOBAL_AS __attribute__((address_space(1)))
#define LDS_AS __attribute__((address_space(3)))

#define D_DIM 768
#define NTOK 1024
#define NSLOT 16
#define NB 32
#define HDIM 512   // H*DH
#define INNER 3072
#define SCALE_D 0.03608439182435161f   // 768^-0.5
#define SCALE_H 0.125f                 // 64^-0.5

// ---------- MFMA GEMM 128x128 (the big M=32768 GEMM) ----------
// C[M,N](f16) = A[M,K] @ Bt[N,K]^T. BK=32, 256 thr, 4 waves 2x2 of 64x64.
// grid = (N/128, M/128): n-tile fastest => resident blocks share A panels (L3 locality).
__global__ __launch_bounds__(256) void mgemm128_k(
    const f16* __restrict__ A, const f16* __restrict__ Bt,
    f16* __restrict__ Cout, int M, int N, int K)
{
  __shared__ __align__(16) f16 As[128*32];
  __shared__ __align__(16) f16 Bs[128*32];
  const int tid = threadIdx.x;
  const int lane = tid & 63;
  const int wave = tid >> 6;
  const int m0 = blockIdx.y*128, n0 = blockIdx.x*128;
  const int wm = (wave>>1)*64, wn = (wave&1)*64;
  const int quad = lane>>4, l16 = lane&15;

  const int sr = tid>>2;           // 0..63
  const int sc = (tid&3)*8;
  const f16* gA0 = A  + (size_t)(m0 + sr)*K + sc;
  const f16* gA1 = gA0 + (size_t)64*K;
  const f16* gB0 = Bt + (size_t)(n0 + sr)*K + sc;
  const f16* gB1 = gB0 + (size_t)64*K;
  LDS_AS void* lA0 = (LDS_AS void*)&As[(size_t)tid*8];
  LDS_AS void* lA1 = (LDS_AS void*)&As[(size_t)(256+tid)*8];
  LDS_AS void* lB0 = (LDS_AS void*)&Bs[(size_t)tid*8];
  LDS_AS void* lB1 = (LDS_AS void*)&Bs[(size_t)(256+tid)*8];

  const f16* fA = &As[(wm + l16)*32 + quad*8];
  const f16* fB = &Bs[(wn + l16)*32 + quad*8];

  f32x4 acc[4][4] = {};

  for (int k0 = 0; k0 < K; k0 += 32){
    __builtin_amdgcn_global_load_lds((const GLOBAL_AS void*)(gA0 + k0), lA0, 16, 0, 0);
    __builtin_amdgcn_global_load_lds((const GLOBAL_AS void*)(gA1 + k0), lA1, 16, 0, 0);
    __builtin_amdgcn_global_load_lds((const GLOBAL_AS void*)(gB0 + k0), lB0, 16, 0, 0);
    __builtin_amdgcn_global_load_lds((const GLOBAL_AS void*)(gB1 + k0), lB1, 16, 0, 0);
    __syncthreads();
    f16x8 a[4], b[4];
    #pragma unroll
    for (int t=0;t<4;++t) a[t] = *(const f16x8*)(fA + t*16*32);
    #pragma unroll
    for (int t=0;t<4;++t) b[t] = *(const f16x8*)(fB + t*16*32);
    #pragma unroll
    for (int mt=0;mt<4;++mt)
      #pragma unroll
      for (int nt=0;nt<4;++nt)
        acc[mt][nt] = __builtin_amdgcn_mfma_f32_16x16x32_f16(a[mt], b[nt], acc[mt][nt], 0, 0, 0);
    __syncthreads();
  }
  #pragma unroll
  for (int mt=0;mt<4;++mt){
    #pragma unroll
    for (int nt=0;nt<4;++nt){
      int gm = m0 + wm + mt*16 + quad*4;
      int gn = n0 + wn + nt*16 + l16;
      #pragma unroll
      for (int r=0;r<4;++r)
        Cout[(size_t)(gm+r)*N + gn] = (f16)acc[mt][nt][r];
    }
  }
}

// ---------- MFMA GEMM 64x64, BK=128 (4 panels), split-K ----------
// OUT: 0 = f32 store, 1 = f16 store, 2 = f32 atomicAdd.
template<int OUT>
__global__ __launch_bounds__(256) void mgemm64_k(
    const f16* __restrict__ A, const f16* __restrict__ Bt,
    void* __restrict__ Cout, int M, int N, int K, int Kc)
{
  __shared__ __align__(16) f16 As[64*128];
  __shared__ __align__(16) f16 Bs[64*128];
  const int tid = threadIdx.x;
  const int lane = tid & 63;
  const int wave = tid >> 6;
  const int m0 = blockIdx.x*64, n0 = blockIdx.y*64;
  const int kbeg = blockIdx.z * Kc;
  const int wm = (wave>>1)*32, wn = (wave&1)*32;
  const int quad = lane>>4, l16 = lane&15;

  const int sr = tid>>2;
  const int sc = (tid&3)*8;
  const f16* gA = A  + (size_t)(m0+sr)*K + kbeg + sc;
  const f16* gB = Bt + (size_t)(n0+sr)*K + kbeg + sc;
  LDS_AS f16* lA = (LDS_AS f16*)&As[(size_t)tid*8];
  LDS_AS f16* lB = (LDS_AS f16*)&Bs[(size_t)tid*8];

  const f16* fA0 = &As[(wm + l16)*32 + quad*8];
  const f16* fB0 = &Bs[(wn + l16)*32 + quad*8];

  f32x4 acc[2][2] = {};

  for (int k0 = 0; k0 < Kc; k0 += 128){
    #pragma unroll
    for (int p=0;p<4;++p){
      __builtin_amdgcn_global_load_lds((const GLOBAL_AS void*)(gA + k0 + p*32),
                                       (LDS_AS void*)(lA + (size_t)p*2048), 16, 0, 0);
      __builtin_amdgcn_global_load_lds((const GLOBAL_AS void*)(gB + k0 + p*32),
                                       (LDS_AS void*)(lB + (size_t)p*2048), 16, 0, 0);
    }
    __syncthreads();
    #pragma unroll
    for (int p=0;p<4;++p){
      f16x8 a0 = *(const f16x8*)(fA0 + p*2048);
      f16x8 a1 = *(const f16x8*)(fA0 + p*2048 + 16*32);
      f16x8 b0 = *(const f16x8*)(fB0 + p*2048);
      f16x8 b1 = *(const f16x8*)(fB0 + p*2048 + 16*32);
      acc[0][0] = __builtin_amdgcn_mfma_f32_16x16x32_f16(a0,b0,acc[0][0],0,0,0);
      acc[0][1] = __builtin_amdgcn_mfma_f32_16x16x32_f16(a0,b1,acc[0][1],0,0,0);
      acc[1][0] = __builtin_amdgcn_mfma_f32_16x16x32_f16(a1,b0,acc[1][0],0,0,0);
      acc[1][1] = __builtin_amdgcn_mfma_f32_16x16x32_f16(a1,b1,acc[1][1],0,0,0);
    }
    __syncthreads();
  }
  #pragma unroll
  for (int mt=0;mt<2;++mt){
    #pragma unroll
    for (int nt=0;nt<2;++nt){
      int gm = m0 + wm + mt*16 + quad*4;
      int gn = n0 + wn + nt*16 + l16;
      #pragma unroll
      for (int r=0;r<4;++r){
        float c = acc[mt][nt][r];
        size_t idx = (size_t)(gm+r)*N + gn;
        if (OUT==0)      ((float*)Cout)[idx] = c;
        else if (OUT==1) ((f16*)Cout)[idx] = (f16)c;
        else             atomicAdd(&((float*)Cout)[idx], c);
      }
    }
  }
}

// ---------- W1 + GLU fused: act[M,3072] = u * silu(g), [u|g] = A @ W1 ----------
// Block: 64 m x 64 c; stages u-cols and matching g-cols (dual B). grid (M/64, 3072/64).
__global__ __launch_bounds__(256) void w1glu_k(
    const f16* __restrict__ A,    // [M,768]
    const f16* __restrict__ W1T,  // [6144,768] rows: 0..3071 = u cols, 3072..6143 = g cols
    f16* __restrict__ act,        // [M,3072]
    int M)
{
  __shared__ __align__(16) f16 As[64*128];
  __shared__ __align__(16) f16 Bu[64*128];
  __shared__ __align__(16) f16 Bg[64*128];
  const int K = 768;
  const int tid = threadIdx.x;
  const int lane = tid & 63;
  const int wave = tid >> 6;
  const int m0 = blockIdx.x*64, n0 = blockIdx.y*64;
  const int wm = (wave>>1)*32, wn = (wave&1)*32;
  const int quad = lane>>4, l16 = lane&15;

  const int sr = tid>>2;
  const int sc = (tid&3)*8;
  const f16* gA  = A   + (size_t)(m0+sr)*K + sc;
  const f16* gBu = W1T + (size_t)(n0+sr)*K + sc;
  const f16* gBg = W1T + (size_t)(3072+n0+sr)*K + sc;
  LDS_AS f16* lA  = (LDS_AS f16*)&As[(size_t)tid*8];
  LDS_AS f16* lBu = (LDS_AS f16*)&Bu[(size_t)tid*8];
  LDS_AS f16* lBg = (LDS_AS f16*)&Bg[(size_t)tid*8];

  const f16* fA0 = &As[(wm + l16)*32 + quad*8];
  const f16* fU0 = &Bu[(wn + l16)*32 + quad*8];
  const f16* fG0 = &Bg[(wn + l16)*32 + quad*8];

  f32x4 accU[2][2] = {};
  f32x4 accG[2][2] = {};

  for (int k0 = 0; k0 < K; k0 += 128){
    #pragma unroll
    for (int p=0;p<4;++p){
      __builtin_amdgcn_global_load_lds((const GLOBAL_AS void*)(gA  + k0 + p*32),
                                       (LDS_AS void*)(lA  + (size_t)p*2048), 16, 0, 0);
      __builtin_amdgcn_global_load_lds((const GLOBAL_AS void*)(gBu + k0 + p*32),
                                       (LDS_AS void*)(lBu + (size_t)p*2048), 16, 0, 0);
      __builtin_amdgcn_global_load_lds((const GLOBAL_AS void*)(gBg + k0 + p*32),
                                       (LDS_AS void*)(lBg + (size_t)p*2048), 16, 0, 0);
    }
    __syncthreads();
    #pragma unroll
    for (int p=0;p<4;++p){
      f16x8 a0 = *(const f16x8*)(fA0 + p*2048);
      f16x8 a1 = *(const f16x8*)(fA0 + p*2048 + 16*32);
      f16x8 u0 = *(const f16x8*)(fU0 + p*2048);
      f16x8 u1 = *(const f16x8*)(fU0 + p*2048 + 16*32);
      f16x8 g0 = *(const f16x8*)(fG0 + p*2048);
      f16x8 g1 = *(const f16x8*)(fG0 + p*2048 + 16*32);
      accU[0][0] = __builtin_amdgcn_mfma_f32_16x16x32_f16(a0,u0,accU[0][0],0,0,0);
      accU[0][1] = __builtin_amdgcn_mfma_f32_16x16x32_f16(a0,u1,accU[0][1],0,0,0);
      accU[1][0] = __builtin_amdgcn_mfma_f32_16x16x32_f16(a1,u0,accU[1][0],0,0,0);
      accU[1][1] = __builtin_amdgcn_mfma_f32_16x16x32_f16(a1,u1,accU[1][1],0,0,0);
      accG[0][0] = __builtin_amdgcn_mfma_f32_16x16x32_f16(a0,g0,accG[0][0],0,0,0);
      accG[0][1] = __builtin_amdgcn_mfma_f32_16x16x32_f16(a0,g1,accG[0][1],0,0,0);
      accG[1][0] = __builtin_amdgcn_mfma_f32_16x16x32_f16(a1,g0,accG[1][0],0,0,0);
      accG[1][1] = __builtin_amdgcn_mfma_f32_16x16x32_f16(a1,g1,accG[1][1],0,0,0);
    }
    __syncthreads();
  }
  #pragma unroll
  for (int mt=0;mt<2;++mt){
    #pragma unroll
    for (int nt=0;nt<2;++nt){
      int gm = m0 + wm + mt*16 + quad*4;
      int gn = n0 + wn + nt*16 + l16;
      #pragma unroll
      for (int r=0;r<4;++r){
        float u = accU[mt][nt][r];
        float g = accG[mt][nt][r];
        float sg = g / (1.0f + __expf(-g));
        act[(size_t)(gm+r)*INNER + gn] = (f16)(u*sg);
      }
    }
  }
}

// ---------- MFMA dots + inverted softmax (over slot axis) + EPS + rowsum ----------
// grid (32, 16): batch x 64-j tile. 4 waves, each one 16-j n-tile.
__global__ __launch_bounds__(256) void dots_k(
    const f16* __restrict__ Q,    // [32,16,768] f16
    const f16* __restrict__ Km,   // [32,1024,1536] f16 (k part of fused kv)
    float* __restrict__ attn,     // [32,16,1024]
    float* __restrict__ rowsum)   // [512]
{
  __shared__ __align__(16) f16 qf[12288];     // A-frag layout: ((ks*4+quad)*16+l16)*8
  __shared__ __align__(16) f16 ksl[64*32];    // [j][k] 32-k slab
  const int b = blockIdx.x, jt = blockIdx.y;
  const int tid = threadIdx.x;
  const int lane = tid & 63;
  const int w = tid >> 6;
  const int quad = lane>>4, l16 = lane&15;

  // stage q into fragment-layout LDS (whole 16x768 tile)
  #pragma unroll
  for (int c=0;c<6;++c){
    int p = c*256 + tid;              // chunk of 8 f16
    int ks = p >> 6;
    int qd = (p >> 4) & 3;
    int rw = p & 15;
    f16x8 v = *(const f16x8*)(Q + ((size_t)(b*NSLOT+rw))*D_DIM + ks*32 + qd*8);
    *(f16x8*)&qf[(size_t)p*8] = v;
  }

  // staging address for k slab: thread t -> j = t>>2, koff = (t&3)*8
  const f16* gK = Km + ((size_t)(b*NTOK + jt*64 + (tid>>2)))*1536 + (tid&3)*8;
  LDS_AS void* lK = (LDS_AS void*)&ksl[(size_t)tid*8];

  f32x4 acc = {};
  for (int ks=0; ks<24; ++ks){
    __builtin_amdgcn_global_load_lds((const GLOBAL_AS void*)(gK + ks*32), lK, 16, 0, 0);
    __syncthreads();
    f16x8 a = *(const f16x8*)&qf[((size_t)(ks*4+quad)*16 + l16)*8];
    f16x8 bfr = *(const f16x8*)&ksl[(size_t)(w*16 + l16)*32 + quad*8];
    acc = __builtin_amdgcn_mfma_f32_16x16x32_f16(a, bfr, acc, 0, 0, 0);
    __syncthreads();
  }

  // C layout: col j = jt*64 + w*16 + l16 ; row i = quad*4 + r
  float v0 = acc[0]*SCALE_D, v1 = acc[1]*SCALE_D, v2 = acc[2]*SCALE_D, v3 = acc[3]*SCALE_D;
  float mx = fmaxf(fmaxf(v0,v1), fmaxf(v2,v3));
  mx = fmaxf(mx, __shfl_xor(mx, 16));
  mx = fmaxf(mx, __shfl_xor(mx, 32));
  float e0 = __expf(v0-mx), e1 = __expf(v1-mx), e2 = __expf(v2-mx), e3 = __expf(v3-mx);
  float s = e0+e1+e2+e3;
  s += __shfl_xor(s, 16);
  s += __shfl_xor(s, 32);
  float inv = 1.0f/s;
  float a0 = e0*inv + 1e-8f, a1 = e1*inv + 1e-8f, a2 = e2*inv + 1e-8f, a3 = e3*inv + 1e-8f;

  int jcol = jt*64 + w*16 + l16;
  int ibase = b*NSLOT + quad*4;
  attn[(size_t)(ibase+0)*NTOK + jcol] = a0;
  attn[(size_t)(ibase+1)*NTOK + jcol] = a1;
  attn[(size_t)(ibase+2)*NTOK + jcol] = a2;
  attn[(size_t)(ibase+3)*NTOK + jcol] = a3;

  float t0=a0, t1=a1, t2=a2, t3=a3;
  #pragma unroll
  for (int m=1;m<16;m<<=1){
    t0 += __shfl_xor(t0, m);
    t1 += __shfl_xor(t1, m);
    t2 += __shfl_xor(t2, m);
    t3 += __shfl_xor(t3, m);
  }
  if (l16 == 0){
    atomicAdd(&rowsum[ibase+0], t0);
    atomicAdd(&rowsum[ibase+1], t1);
    atomicAdd(&rowsum[ibase+2], t2);
    atomicAdd(&rowsum[ibase+3], t3);
  }
}

// ---------- LayerNorm over rows of width 768 ----------
template<bool ADD, int OUT>   // OUT: 0=f32, 1=f16
__global__ __launch_bounds__(256) void ln_k(
    const float* __restrict__ X, const float* __restrict__ X2,
    const float* __restrict__ g, const float* __restrict__ bb,
    void* __restrict__ out)
{
  __shared__ float rs[256], rss[256];
  const int row = blockIdx.x, tid = threadIdx.x;
  const float* x = X + (size_t)row*D_DIM;
  float vals[3]; float s=0.f, ss=0.f;
  #pragma unroll
  for (int t=0;t<3;++t){
    int c = tid + t*256;
    float v = x[c];
    if (ADD) v += X2[(size_t)row*D_DIM + c];
    vals[t]=v; s+=v; ss+=v*v;
  }
  rs[tid]=s; rss[tid]=ss; __syncthreads();
  for (int off=128; off>0; off>>=1){
    if (tid<off){ rs[tid]+=rs[tid+off]; rss[tid]+=rss[tid+off]; }
    __syncthreads();
  }
  float mean = rs[0]*(1.0f/768.0f);
  float var  = rss[0]*(1.0f/768.0f) - mean*mean;
  float inv  = rsqrtf(var + 1e-5f);
  #pragma unroll
  for (int t=0;t<3;++t){
    int c = tid + t*256;
    float y = (vals[t]-mean)*inv*g[c] + bb[c];
    if (OUT==1) ((f16*)out)[(size_t)row*D_DIM + c] = (f16)y;
    else        ((float*)out)[(size_t)row*D_DIM + c] = y;
  }
}

// ---------- fused double LayerNorm ----------
template<bool ADD>
__global__ __launch_bounds__(256) void lnln_k(
    const float* __restrict__ X, const float* __restrict__ X2,
    const float* __restrict__ g1, const float* __restrict__ b1,
    const float* __restrict__ g2, const float* __restrict__ b2,
    float* __restrict__ out1, f16* __restrict__ out2)
{
  __shared__ float rs[256], rss[256];
  const int row = blockIdx.x, tid = threadIdx.x;
  const float* x = X + (size_t)row*D_DIM;
  float vals[3]; float s=0.f, ss=0.f;
  #pragma unroll
  for (int t=0;t<3;++t){
    int c = tid + t*256;
    float v = x[c];
    if (ADD) v += X2[(size_t)row*D_DIM + c];
    vals[t]=v; s+=v; ss+=v*v;
  }
  rs[tid]=s; rss[tid]=ss; __syncthreads();
  for (int off=128; off>0; off>>=1){
    if (tid<off){ rs[tid]+=rs[tid+off]; rss[tid]+=rss[tid+off]; }
    __syncthreads();
  }
  float mean = rs[0]*(1.0f/768.0f);
  float var  = rss[0]*(1.0f/768.0f) - mean*mean;
  float inv  = rsqrtf(var + 1e-5f);
  float y[3]; float s2=0.f, ss2=0.f;
  #pragma unroll
  for (int t=0;t<3;++t){
    int c = tid + t*256;
    float yy = (vals[t]-mean)*inv*g1[c] + b1[c];
    y[t]=yy; s2+=yy; ss2+=yy*yy;
    out1[(size_t)row*D_DIM + c] = yy;
  }
  __syncthreads();
  rs[tid]=s2; rss[tid]=ss2; __syncthreads();
  for (int off=128; off>0; off>>=1){
    if (tid<off){ rs[tid]+=rs[tid+off]; rss[tid]+=rss[tid+off]; }
    __syncthreads();
  }
  float mean2 = rs[0]*(1.0f/768.0f);
  float var2  = rss[0]*(1.0f/768.0f) - mean2*mean2;
  float inv2  = rsqrtf(var2 + 1e-5f);
  #pragma unroll
  for (int t=0;t<3;++t){
    int c = tid + t*256;
    out2[(size_t)row*D_DIM + c] = (f16)((y[t]-mean2)*inv2*g2[c] + b2[c]);
  }
}

// ---------- slots init ----------
__global__ __launch_bounds__(256) void slots_init_k(
    const float* __restrict__ noise, const float* __restrict__ mu,
    const float* __restrict__ ls, float* __restrict__ slots)
{
  int idx = blockIdx.x*256 + threadIdx.x;   // 512*768
  int d = idx % D_DIM;
  slots[idx] = mu[d] + expf(ls[d]) * noise[idx];
}

// ---------- updates = (attn_pre @ V) / rowsum ----------
__global__ __launch_bounds__(256) void attnv_k(
    const float* __restrict__ attn,   // [32,16,1024]
    const float* __restrict__ rowsum, // [512]
    const f16* __restrict__ V,        // [32,1024,KSTR]
    int KSTR,
    float* __restrict__ upd)          // [32,16,768]
{
  __shared__ float as_[16][68];
  __shared__ float vs[64][132];
  const int b = blockIdx.x, dbase = blockIdx.y*128;
  const int tid = threadIdx.x;
  const int ci = tid>>4;
  const int cd = (tid&15)*8;
  float acc[8] = {};
  for (int j0=0; j0<NTOK; j0+=64){
    {
      int i = tid>>4, jj=(tid&15)*4;
      float4 a4 = *(const float4*)&attn[((size_t)b*NSLOT+i)*NTOK + j0 + jj];
      *(float4*)&as_[i][jj] = a4;
    }
    {
      int jj = tid>>2, ds0=(tid&3)*32;
      const f16* p = V + ((size_t)(b*NTOK+j0+jj))*KSTR + dbase + ds0;
      #pragma unroll
      for (int t=0;t<8;++t){
        f16x4 u = *(const f16x4*)(p + t*4);
        float4 f = { (float)u.x, (float)u.y, (float)u.z, (float)u.w };
        *(float4*)&vs[jj][ds0 + t*4] = f;
      }
    }
    __syncthreads();
    #pragma unroll 4
    for (int jj=0;jj<64;++jj){
      float av = as_[ci][jj];
      #pragma unroll
      for (int t=0;t<8;++t) acc[t] += av*vs[jj][cd+t];
    }
    __syncthreads();
  }
  float inv = 1.0f / rowsum[b*NSLOT + ci];
  #pragma unroll
  for (int t=0;t<8;++t)
    upd[((size_t)b*NSLOT+ci)*D_DIM + dbase + cd + t] = acc[t]*inv;
}

// ---------- encoder self-attention (tiny: 16x16 per (b,h)) ----------
__global__ __launch_bounds__(256) void encattn_k(
    const f16* __restrict__ QA, const f16* __restrict__ KA,
    const f16* __restrict__ VA, int QSTR,
    f16* __restrict__ O)        // [32,16,512] f16
{
  __shared__ float qs[16][68], ks[16][68], vs[16][68], ps[16][20];
  const int b = blockIdx.x, h = blockIdx.y;
  const int tid = threadIdx.x;
  {
    int i = tid>>4, dd=(tid&15)*4;
    size_t base = ((size_t)(b*NSLOT+i))*QSTR + h*64 + dd;
    f16x4 uq = *(const f16x4*)(QA + base);
    f16x4 uk = *(const f16x4*)(KA + base);
    f16x4 uv = *(const f16x4*)(VA + base);
    float4 fq = { (float)uq.x, (float)uq.y, (float)uq.z, (float)uq.w };
    float4 fk = { (float)uk.x, (float)uk.y, (float)uk.z, (float)uk.w };
    float4 fv = { (float)uv.x, (float)uv.y, (float)uv.z, (float)uv.w };
    *(float4*)&qs[i][dd]=fq; *(float4*)&ks[i][dd]=fk; *(float4*)&vs[i][dd]=fv;
  }
  __syncthreads();
  {
    int i = tid>>4, j = tid&15;
    float s=0.f;
    #pragma unroll 8
    for (int d=0; d<64; ++d) s += qs[i][d]*ks[j][d];
    ps[i][j] = s*SCALE_H;
  }
  __syncthreads();
  if (tid < 16){
    int i = tid;
    float mx=-1e30f;
    #pragma unroll
    for (int j=0;j<16;++j) mx = fmaxf(mx, ps[i][j]);
    float sm=0.f;
    #pragma unroll
    for (int j=0;j<16;++j){ float e=__expf(ps[i][j]-mx); ps[i][j]=e; sm+=e; }
    float inv=1.0f/sm;
    #pragma unroll
    for (int j=0;j<16;++j) ps[i][j]*=inv;
  }
  __syncthreads();
  {
    int i = tid>>4, dq=(tid&15)*4;
    float a0=0,a1=0,a2=0,a3=0;
    #pragma unroll
    for (int j=0;j<16;++j){
      float p = ps[i][j];
      a0+=p*vs[j][dq+0]; a1+=p*vs[j][dq+1]; a2+=p*vs[j][dq+2]; a3+=p*vs[j][dq+3];
    }
    size_t base = ((size_t)(b*NSLOT+i))*HDIM + h*64 + dq;
    O[base+0]=(f16)a0; O[base+1]=(f16)a1; O[base+2]=(f16)a2; O[base+3]=(f16)a3;
  }
}

// ---------- f32 -> f16 transposed cast: out[C][R] = in[R][C] ----------
__global__ __launch_bounds__(256) void cast_t_k(
    const float* __restrict__ in, f16* __restrict__ out, int R, int C)
{
  __shared__ float t[32][33];
  int r0 = blockIdx.x*32, c0 = blockIdx.y*32;
  int tr = threadIdx.x & 31, g8 = threadIdx.x >> 5;
  #pragma unroll
  for (int s=0;s<4;++s){
    int r = g8*4 + s;
    t[r][tr] = in[(size_t)(r0+r)*C + c0+tr];
  }
  __syncthreads();
  #pragma unroll
  for (int s=0;s<4;++s){
    int c = g8*4+s;
    out[(size_t)(c0+c)*R + r0+tr] = (f16)t[tr][c];
  }
}

// ---------- attn_map output: out[b,j,i] = attn[b,i,j]/rowsum[b,i] ----------
__global__ __launch_bounds__(256) void attnout_k(
    const float* __restrict__ attn, const float* __restrict__ rowsum,
    float* __restrict__ out)
{
  int idx = blockIdx.x*256 + threadIdx.x;  // 32*1024*16
  int i = idx & 15;
  int j = (idx >> 4) & 1023;
  int b = idx >> 14;
  out[idx] = attn[((size_t)b*NSLOT+i)*NTOK + j] / rowsum[b*NSLOT + i];
}

extern "C" void kernel_launch(void* const* d_in, const int* in_sizes, int n_in,
                              void* d_out, int out_size, void* d_ws, size_t ws_size,
                              hipStream_t stream) {
  const float* x        = (const float*)d_in[0];
  const float* noise    = (const float*)d_in[1];
  const float* init_mu  = (const float*)d_in[2];
  const float* init_ls  = (const float*)d_in[3];
  const float* Wk       = (const float*)d_in[4];
  const float* Wv       = (const float*)d_in[5];
  const float* Wq       = (const float*)d_in[6];
  const float* ni_g     = (const float*)d_in[7];
  const float* ni_b     = (const float*)d_in[8];
  const float* ns_g     = (const float*)d_in[9];
  const float* ns_b     = (const float*)d_in[10];
  const float* nica_g   = (const float*)d_in[11];
  const float* nica_b   = (const float*)d_in[12];
  const float* ln1_g    = (const float*)d_in[13];
  const float* ln1_b    = (const float*)d_in[14];
  const float* Wq_a     = (const float*)d_in[15];
  const float* Wk_a     = (const float*)d_in[16];
  const float* Wv_a     = (const float*)d_in[17];
  const float* Wo_a     = (const float*)d_in[18];
  const float* ln2_g    = (const float*)d_in[19];
  const float* ln2_b    = (const float*)d_in[20];
  const float* W1       = (const float*)d_in[21];
  const float* W2       = (const float*)d_in[22];
  const float* lnf_g    = (const float*)d_in[23];
  const float* lnf_b    = (const float*)d_in[24];

  // ---- workspace layout ----
  char* w = (char*)d_ws;
  size_t off = 0;
  auto alloc = [&](size_t bytes)->char*{
    char* p = w + off; off += (bytes + 255) & ~(size_t)255; return p;
  };
  f16* xn_h  = (f16*)alloc((size_t)NB*NTOK*D_DIM*2);      // 48 MB
  f16* kv_h  = (f16*)alloc((size_t)NB*NTOK*1536*2);       // 96 MB (k | v fused)
  f16* WkvT  = (f16*)alloc((size_t)1536*768*2);
  f16* WqT   = (f16*)alloc((size_t)768*768*2);
  f16* WqkvT = (f16*)alloc((size_t)1536*768*2);
  f16* WoaT  = (f16*)alloc((size_t)768*512*2);
  f16* W1T   = (f16*)alloc((size_t)6144*768*2);
  f16* W2T   = (f16*)alloc((size_t)768*3072*2);
  float* slots = (float*)alloc(512*768*4);
  float* hbuf  = (float*)alloc(512*768*4);
  float* upd   = (float*)alloc(512*768*4);
  f16* tmp_h  = (f16*)alloc(512*768*2);
  f16* tmp2_h = (f16*)alloc(512*768*2);
  f16* q_h    = (f16*)alloc(512*768*2);
  f16* qkv_h  = (f16*)alloc((size_t)512*1536*2);
  f16* o_h    = (f16*)alloc(512*512*2);
  f16* act_h  = (f16*)alloc((size_t)512*3072*2);
  float* attn_pre = (float*)alloc((size_t)NB*NSLOT*NTOK*4);
  float* rowsum = (float*)alloc(512*4);

  // ---- cast weights to f16, transposed ([N][K] for gemm Bt) ----
  auto castT = [&](const float* src, f16* dst, int R, int C){
    cast_t_k<<<dim3(R/32, C/32), 256, 0, stream>>>(src, dst, R, C);
  };
  castT(Wk,   WkvT,            768, 768);
  castT(Wv,   WkvT + 768*768,  768, 768);
  castT(Wq,   WqT,             768, 768);
  castT(Wq_a, WqkvT,             768, 512);
  castT(Wk_a, WqkvT + 512*768,   768, 512);
  castT(Wv_a, WqkvT + 1024*768,  768, 512);
  castT(Wo_a, WoaT,            512, 768);
  castT(W1,   W1T,             768, 6144);
  castT(W2,   W2T,             3072, 768);

  // ---- xn = LN(x); kv = xn @ [Wk|Wv] (fused, n-fastest grid) ----
  ln_k<false,1><<<NB*NTOK, 256, 0, stream>>>(x, nullptr, ni_g, ni_b, xn_h);
  mgemm128_k<<<dim3(1536/128, NB*NTOK/128), 256, 0, stream>>>(xn_h, WkvT, kv_h, NB*NTOK, 1536, 768);

  // ---- slots init + first LN(slots, ns) ----
  slots_init_k<<<512*768/256, 256, 0, stream>>>(noise, init_mu, init_ls, slots);
  ln_k<false,1><<<512, 256, 0, stream>>>(slots, nullptr, ns_g, ns_b, tmp2_h);

  // ---- 4 iterations ----
  for (int it=0; it<4; ++it){
    hipMemsetAsync(rowsum, 0, 512*4, stream);
    // q = LN(slots,ns) @ Wq  (plain f16 store)
    mgemm64_k<1><<<dim3(8, 12, 1), 256, 0, stream>>>(tmp2_h, WqT, q_h, 512, 768, 768, 768);
    // dots + inverted softmax (MFMA)
    dots_k<<<dim3(NB, 16), 256, 0, stream>>>(q_h, kv_h, attn_pre, rowsum);
    // updates = (attn/rowsum) @ v
    attnv_k<<<dim3(NB, D_DIM/128), 256, 0, stream>>>(attn_pre, rowsum, kv_h + 768, 1536, upd);
    // h = LN(slots+upd, nica) -> hbuf ; a = LN(h, ln1) -> tmp_h
    lnln_k<true><<<512, 256, 0, stream>>>(slots, upd, nica_g, nica_b, ln1_g, ln1_b, hbuf, tmp_h);
    // qkv = a @ [Wq_a|Wk_a|Wv_a]
    mgemm64_k<1><<<dim3(8, 24, 1), 256, 0, stream>>>(tmp_h, WqkvT, qkv_h, 512, 1536, 768, 768);
    encattn_k<<<dim3(NB, 8), 256, 0, stream>>>(qkv_h, qkv_h + 512, qkv_h + 1024, 1536, o_h);
    // h += o @ Wo_a  (split-K=2, atomic into hbuf)
    mgemm64_k<2><<<dim3(8, 12, 2), 256, 0, stream>>>(o_h, WoaT, hbuf, 512, 768, 512, 256);
    // f = LN(h, ln2)
    ln_k<false,1><<<512, 256, 0, stream>>>(hbuf, nullptr, ln2_g, ln2_b, tmp_h);
    // act = glu(f @ W1)  (fused)
    w1glu_k<<<dim3(8, 48), 256, 0, stream>>>(tmp_h, W1T, act_h, 512);
    // h += act @ W2  (split-K=4, atomic into hbuf)
    mgemm64_k<2><<<dim3(8, 12, 4), 256, 0, stream>>>(act_h, W2T, hbuf, 512, 768, 3072, 768);
    // slots = LN(h, lnf) ; tmp2 = LN(slots, ns) for next iter's q proj
    lnln_k<false><<<512, 256, 0, stream>>>(hbuf, nullptr, lnf_g, lnf_b, ns_g, ns_b, slots, tmp2_h);
  }

  // ---- outputs: slots, then attn_map (transposed, normalized) ----
  hipMemcpyAsync(d_out, slots, (size_t)512*768*4, hipMemcpyDeviceToDevice, stream);
  attnout_k<<<NB*NTOK*NSLOT/256, 256, 0, stream>>>(attn_pre, rowsum, (float*)d_out + 512*768);
}

// Round 5
// 742.304 us; speedup vs baseline: 5.0820x; 1.2384x over previous
//
#include <hip/hip_runtime.h>
#include <hip/hip_bf16.h>
#include <stdint.h>

typedef _Float16 f16;
typedef __attribute__((ext_vector_type(8))) _Float16 f16x8;
typedef __attribute__((ext_vector_type(4))) _Float16 f16x4;
typedef __attribute__((ext_vector_type(4))) float f32x4;

#define GLOBAL_AS __attribute__((address_space(1)))
#define LDS_AS __attribute__((address_space(3)))

#define D_DIM 768
#define NTOK 1024
#define NSLOT 16
#define NB 32
#define NTOT (NB*NTOK)   // 32768
#define HDIM 512
#define INNER 3072
#define SCALE_D 0.03608439182435161f   // 768^-0.5
#define SCALE_H 0.125f                 // 64^-0.5

// ---------- big GEMM: [k | vT] = xn @ [Wk|Wv], 128x128 tile, BK=64 (2 panels) ----------
// n0 < 768  -> Kout[m][n] (f16 scalar stores)
// n0 >= 768 -> VTout[n-768][m] (packed f16x4 stores)
__global__ __launch_bounds__(256) void mgemm128_k(
    const f16* __restrict__ A, const f16* __restrict__ Bt,
    f16* __restrict__ Kout, f16* __restrict__ VTout, int M, int K)
{
  __shared__ __align__(16) f16 As[128*64];   // 2 panels of [128][32]
  __shared__ __align__(16) f16 Bs[128*64];
  const int tid = threadIdx.x;
  const int lane = tid & 63;
  const int wave = tid >> 6;
  const int m0 = blockIdx.y*128, n0 = blockIdx.x*128;
  const int wm = (wave>>1)*64, wn = (wave&1)*64;
  const int quad = lane>>4, l16 = lane&15;

  const int sr = tid>>2;
  const int sc = (tid&3)*8;
  const f16* gA0 = A  + (size_t)(m0 + sr)*K + sc;
  const f16* gA1 = gA0 + (size_t)64*K;
  const f16* gB0 = Bt + (size_t)(n0 + sr)*K + sc;
  const f16* gB1 = gB0 + (size_t)64*K;

  f32x4 acc[4][4] = {};

  for (int k0 = 0; k0 < K; k0 += 64){
    #pragma unroll
    for (int p=0;p<2;++p){
      __builtin_amdgcn_global_load_lds((const GLOBAL_AS void*)(gA0 + k0 + p*32),
          (LDS_AS void*)&As[p*4096 + tid*8], 16, 0, 0);
      __builtin_amdgcn_global_load_lds((const GLOBAL_AS void*)(gA1 + k0 + p*32),
          (LDS_AS void*)&As[p*4096 + (256+tid)*8], 16, 0, 0);
      __builtin_amdgcn_global_load_lds((const GLOBAL_AS void*)(gB0 + k0 + p*32),
          (LDS_AS void*)&Bs[p*4096 + tid*8], 16, 0, 0);
      __builtin_amdgcn_global_load_lds((const GLOBAL_AS void*)(gB1 + k0 + p*32),
          (LDS_AS void*)&Bs[p*4096 + (256+tid)*8], 16, 0, 0);
    }
    __syncthreads();
    #pragma unroll
    for (int p=0;p<2;++p){
      const f16* fA = &As[p*4096 + (wm + l16)*32 + quad*8];
      const f16* fB = &Bs[p*4096 + (wn + l16)*32 + quad*8];
      f16x8 a[4], b[4];
      #pragma unroll
      for (int t=0;t<4;++t) a[t] = *(const f16x8*)(fA + t*16*32);
      #pragma unroll
      for (int t=0;t<4;++t) b[t] = *(const f16x8*)(fB + t*16*32);
      #pragma unroll
      for (int mt=0;mt<4;++mt)
        #pragma unroll
        for (int nt=0;nt<4;++nt)
          acc[mt][nt] = __builtin_amdgcn_mfma_f32_16x16x32_f16(a[mt], b[nt], acc[mt][nt], 0, 0, 0);
    }
    __syncthreads();
  }

  if (n0 < 768){
    #pragma unroll
    for (int mt=0;mt<4;++mt)
      #pragma unroll
      for (int nt=0;nt<4;++nt){
        int gm = m0 + wm + mt*16 + quad*4;
        int gn = n0 + wn + nt*16 + l16;
        #pragma unroll
        for (int r=0;r<4;++r)
          Kout[(size_t)(gm+r)*768 + gn] = (f16)acc[mt][nt][r];
      }
  } else {
    #pragma unroll
    for (int mt=0;mt<4;++mt)
      #pragma unroll
      for (int nt=0;nt<4;++nt){
        int gm = m0 + wm + mt*16 + quad*4;
        int gn = n0 - 768 + wn + nt*16 + l16;
        f16x4 v4 = { (f16)acc[mt][nt][0], (f16)acc[mt][nt][1],
                     (f16)acc[mt][nt][2], (f16)acc[mt][nt][3] };
        *(f16x4*)&VTout[(size_t)gn*M + gm] = v4;
      }
  }
}

// ---------- MFMA GEMM 64x64, BK=128 (4 panels), split-K ----------
// OUT: 0 = f32 store, 1 = f16 store, 2 = f32 atomicAdd.
template<int OUT>
__global__ __launch_bounds__(256) void mgemm64_k(
    const f16* __restrict__ A, const f16* __restrict__ Bt,
    void* __restrict__ Cout, int M, int N, int K, int Kc)
{
  __shared__ __align__(16) f16 As[64*128];
  __shared__ __align__(16) f16 Bs[64*128];
  const int tid = threadIdx.x;
  const int lane = tid & 63;
  const int wave = tid >> 6;
  const int m0 = blockIdx.x*64, n0 = blockIdx.y*64;
  const int kbeg = blockIdx.z * Kc;
  const int wm = (wave>>1)*32, wn = (wave&1)*32;
  const int quad = lane>>4, l16 = lane&15;

  const int sr = tid>>2;
  const int sc = (tid&3)*8;
  const f16* gA = A  + (size_t)(m0+sr)*K + kbeg + sc;
  const f16* gB = Bt + (size_t)(n0+sr)*K + kbeg + sc;
  LDS_AS f16* lA = (LDS_AS f16*)&As[(size_t)tid*8];
  LDS_AS f16* lB = (LDS_AS f16*)&Bs[(size_t)tid*8];

  const f16* fA0 = &As[(wm + l16)*32 + quad*8];
  const f16* fB0 = &Bs[(wn + l16)*32 + quad*8];

  f32x4 acc[2][2] = {};

  for (int k0 = 0; k0 < Kc; k0 += 128){
    #pragma unroll
    for (int p=0;p<4;++p){
      __builtin_amdgcn_global_load_lds((const GLOBAL_AS void*)(gA + k0 + p*32),
                                       (LDS_AS void*)(lA + (size_t)p*2048), 16, 0, 0);
      __builtin_amdgcn_global_load_lds((const GLOBAL_AS void*)(gB + k0 + p*32),
                                       (LDS_AS void*)(lB + (size_t)p*2048), 16, 0, 0);
    }
    __syncthreads();
    #pragma unroll
    for (int p=0;p<4;++p){
      f16x8 a0 = *(const f16x8*)(fA0 + p*2048);
      f16x8 a1 = *(const f16x8*)(fA0 + p*2048 + 16*32);
      f16x8 b0 = *(const f16x8*)(fB0 + p*2048);
      f16x8 b1 = *(const f16x8*)(fB0 + p*2048 + 16*32);
      acc[0][0] = __builtin_amdgcn_mfma_f32_16x16x32_f16(a0,b0,acc[0][0],0,0,0);
      acc[0][1] = __builtin_amdgcn_mfma_f32_16x16x32_f16(a0,b1,acc[0][1],0,0,0);
      acc[1][0] = __builtin_amdgcn_mfma_f32_16x16x32_f16(a1,b0,acc[1][0],0,0,0);
      acc[1][1] = __builtin_amdgcn_mfma_f32_16x16x32_f16(a1,b1,acc[1][1],0,0,0);
    }
    __syncthreads();
  }
  #pragma unroll
  for (int mt=0;mt<2;++mt){
    #pragma unroll
    for (int nt=0;nt<2;++nt){
      int gm = m0 + wm + mt*16 + quad*4;
      int gn = n0 + wn + nt*16 + l16;
      #pragma unroll
      for (int r=0;r<4;++r){
        float c = acc[mt][nt][r];
        size_t idx = (size_t)(gm+r)*N + gn;
        if (OUT==0)      ((float*)Cout)[idx] = c;
        else if (OUT==1) ((f16*)Cout)[idx] = (f16)c;
        else             atomicAdd(&((float*)Cout)[idx], c);
      }
    }
  }
}

// ---------- W1 + GLU fused ----------
__global__ __launch_bounds__(256) void w1glu_k(
    const f16* __restrict__ A, const f16* __restrict__ W1T,
    f16* __restrict__ act, int M)
{
  __shared__ __align__(16) f16 As[64*128];
  __shared__ __align__(16) f16 Bu[64*128];
  __shared__ __align__(16) f16 Bg[64*128];
  const int K = 768;
  const int tid = threadIdx.x;
  const int lane = tid & 63;
  const int wave = tid >> 6;
  const int m0 = blockIdx.x*64, n0 = blockIdx.y*64;
  const int wm = (wave>>1)*32, wn = (wave&1)*32;
  const int quad = lane>>4, l16 = lane&15;

  const int sr = tid>>2;
  const int sc = (tid&3)*8;
  const f16* gA  = A   + (size_t)(m0+sr)*K + sc;
  const f16* gBu = W1T + (size_t)(n0+sr)*K + sc;
  const f16* gBg = W1T + (size_t)(3072+n0+sr)*K + sc;
  LDS_AS f16* lA  = (LDS_AS f16*)&As[(size_t)tid*8];
  LDS_AS f16* lBu = (LDS_AS f16*)&Bu[(size_t)tid*8];
  LDS_AS f16* lBg = (LDS_AS f16*)&Bg[(size_t)tid*8];

  const f16* fA0 = &As[(wm + l16)*32 + quad*8];
  const f16* fU0 = &Bu[(wn + l16)*32 + quad*8];
  const f16* fG0 = &Bg[(wn + l16)*32 + quad*8];

  f32x4 accU[2][2] = {};
  f32x4 accG[2][2] = {};

  for (int k0 = 0; k0 < K; k0 += 128){
    #pragma unroll
    for (int p=0;p<4;++p){
      __builtin_amdgcn_global_load_lds((const GLOBAL_AS void*)(gA  + k0 + p*32),
                                       (LDS_AS void*)(lA  + (size_t)p*2048), 16, 0, 0);
      __builtin_amdgcn_global_load_lds((const GLOBAL_AS void*)(gBu + k0 + p*32),
                                       (LDS_AS void*)(lBu + (size_t)p*2048), 16, 0, 0);
      __builtin_amdgcn_global_load_lds((const GLOBAL_AS void*)(gBg + k0 + p*32),
                                       (LDS_AS void*)(lBg + (size_t)p*2048), 16, 0, 0);
    }
    __syncthreads();
    #pragma unroll
    for (int p=0;p<4;++p){
      f16x8 a0 = *(const f16x8*)(fA0 + p*2048);
      f16x8 a1 = *(const f16x8*)(fA0 + p*2048 + 16*32);
      f16x8 u0 = *(const f16x8*)(fU0 + p*2048);
      f16x8 u1 = *(const f16x8*)(fU0 + p*2048 + 16*32);
      f16x8 g0 = *(const f16x8*)(fG0 + p*2048);
      f16x8 g1 = *(const f16x8*)(fG0 + p*2048 + 16*32);
      accU[0][0] = __builtin_amdgcn_mfma_f32_16x16x32_f16(a0,u0,accU[0][0],0,0,0);
      accU[0][1] = __builtin_amdgcn_mfma_f32_16x16x32_f16(a0,u1,accU[0][1],0,0,0);
      accU[1][0] = __builtin_amdgcn_mfma_f32_16x16x32_f16(a1,u0,accU[1][0],0,0,0);
      accU[1][1] = __builtin_amdgcn_mfma_f32_16x16x32_f16(a1,u1,accU[1][1],0,0,0);
      accG[0][0] = __builtin_amdgcn_mfma_f32_16x16x32_f16(a0,g0,accG[0][0],0,0,0);
      accG[0][1] = __builtin_amdgcn_mfma_f32_16x16x32_f16(a0,g1,accG[0][1],0,0,0);
      accG[1][0] = __builtin_amdgcn_mfma_f32_16x16x32_f16(a1,g0,accG[1][0],0,0,0);
      accG[1][1] = __builtin_amdgcn_mfma_f32_16x16x32_f16(a1,g1,accG[1][1],0,0,0);
    }
    __syncthreads();
  }
  #pragma unroll
  for (int mt=0;mt<2;++mt){
    #pragma unroll
    for (int nt=0;nt<2;++nt){
      int gm = m0 + wm + mt*16 + quad*4;
      int gn = n0 + wn + nt*16 + l16;
      #pragma unroll
      for (int r=0;r<4;++r){
        float u = accU[mt][nt][r];
        float g = accG[mt][nt][r];
        float sg = g / (1.0f + __expf(-g));
        act[(size_t)(gm+r)*INNER + gn] = (f16)(u*sg);
      }
    }
  }
}

// ---------- MFMA dots + inverted softmax + EPS + rowsum (BK=128) ----------
// grid (32, 16): batch x 64-j tile. Writes attn f16.
__global__ __launch_bounds__(256) void dots_k(
    const f16* __restrict__ Q,    // [32,16,768]
    const f16* __restrict__ Kh,   // [32768,768]
    f16* __restrict__ attn,       // [32,16,1024] f16
    float* __restrict__ rowsum)   // [512]
{
  __shared__ __align__(16) f16 qf[16*768];    // A-frag layout, 24 KB
  __shared__ __align__(16) f16 ks[64*128];    // 4 panels [64][32], 16 KB
  const int b = blockIdx.x, jt = blockIdx.y;
  const int tid = threadIdx.x;
  const int lane = tid & 63;
  const int w = tid >> 6;
  const int quad = lane>>4, l16 = lane&15;

  // prestage q into frag layout: chunk p -> (ks_idx=p>>6, qd=(p>>4)&3, rw=p&15)
  #pragma unroll
  for (int c=0;c<6;++c){
    int p = c*256 + tid;
    int ki = p >> 6, qd = (p >> 4) & 3, rw = p & 15;
    f16x8 v = *(const f16x8*)(Q + ((size_t)(b*NSLOT+rw))*D_DIM + ki*32 + qd*8);
    *(f16x8*)&qf[(size_t)p*8] = v;
  }

  const f16* gK = Kh + ((size_t)(b*NTOK + jt*64 + (tid>>2)))*D_DIM + (tid&3)*8;
  LDS_AS f16* lK = (LDS_AS f16*)&ks[(size_t)tid*8];

  f32x4 acc = {};
  for (int it=0; it<6; ++it){
    #pragma unroll
    for (int p=0;p<4;++p)
      __builtin_amdgcn_global_load_lds((const GLOBAL_AS void*)(gK + it*128 + p*32),
                                       (LDS_AS void*)(lK + (size_t)p*2048), 16, 0, 0);
    __syncthreads();
    #pragma unroll
    for (int p=0;p<4;++p){
      f16x8 a  = *(const f16x8*)&qf[(((size_t)(it*4+p)*4 + quad)*16 + l16)*8];
      f16x8 bf = *(const f16x8*)&ks[(size_t)p*2048 + (w*16+l16)*32 + quad*8];
      acc = __builtin_amdgcn_mfma_f32_16x16x32_f16(a, bf, acc, 0, 0, 0);
    }
    __syncthreads();
  }

  float v0 = acc[0]*SCALE_D, v1 = acc[1]*SCALE_D, v2 = acc[2]*SCALE_D, v3 = acc[3]*SCALE_D;
  float mx = fmaxf(fmaxf(v0,v1), fmaxf(v2,v3));
  mx = fmaxf(mx, __shfl_xor(mx, 16));
  mx = fmaxf(mx, __shfl_xor(mx, 32));
  float e0 = __expf(v0-mx), e1 = __expf(v1-mx), e2 = __expf(v2-mx), e3 = __expf(v3-mx);
  float s = e0+e1+e2+e3;
  s += __shfl_xor(s, 16);
  s += __shfl_xor(s, 32);
  float inv = 1.0f/s;
  float a0 = e0*inv + 1e-8f, a1 = e1*inv + 1e-8f, a2 = e2*inv + 1e-8f, a3 = e3*inv + 1e-8f;

  int jcol = jt*64 + w*16 + l16;
  int ibase = b*NSLOT + quad*4;
  attn[(size_t)(ibase+0)*NTOK + jcol] = (f16)a0;
  attn[(size_t)(ibase+1)*NTOK + jcol] = (f16)a1;
  attn[(size_t)(ibase+2)*NTOK + jcol] = (f16)a2;
  attn[(size_t)(ibase+3)*NTOK + jcol] = (f16)a3;

  float t0=a0, t1=a1, t2=a2, t3=a3;
  #pragma unroll
  for (int m=1;m<16;m<<=1){
    t0 += __shfl_xor(t0, m);
    t1 += __shfl_xor(t1, m);
    t2 += __shfl_xor(t2, m);
    t3 += __shfl_xor(t3, m);
  }
  if (l16 == 0){
    atomicAdd(&rowsum[ibase+0], t0);
    atomicAdd(&rowsum[ibase+1], t1);
    atomicAdd(&rowsum[ibase+2], t2);
    atomicAdd(&rowsum[ibase+3], t3);
  }
}

// ---------- updates = (attn @ v) / rowsum via MFMA, B = vT ----------
// grid (32 b, 12 d-tiles of 64). M=16 slots, K=1024 keys, BK=128.
__global__ __launch_bounds__(256) void attnv_k(
    const f16* __restrict__ attn,   // [32,16,1024] f16
    const float* __restrict__ rowsum,
    const f16* __restrict__ VT,     // [768, 32768]
    float* __restrict__ upd)        // [32,16,768] f32
{
  __shared__ __align__(16) f16 Asl[16*128];   // 4 panels [16][32], 4 KB
  __shared__ __align__(16) f16 Bsl[64*128];   // 4 panels [64][32], 16 KB
  const int b = blockIdx.x, d0 = blockIdx.y*64;
  const int tid = threadIdx.x;
  const int lane = tid & 63;
  const int w = tid >> 6;
  const int quad = lane>>4, l16 = lane&15;

  const int pa = tid>>6, ta = tid&63;
  const f16* gA = attn + ((size_t)(b*NSLOT + (ta>>2)))*NTOK + pa*32 + (ta&3)*8;
  LDS_AS f16* lA = (LDS_AS f16*)&Asl[(size_t)pa*512 + ta*8];
  const f16* gB = VT + ((size_t)(d0 + (tid>>2)))*NTOT + b*NTOK + (tid&3)*8;
  LDS_AS f16* lB = (LDS_AS f16*)&Bsl[(size_t)tid*8];

  f32x4 acc = {};
  for (int it=0; it<8; ++it){
    __builtin_amdgcn_global_load_lds((const GLOBAL_AS void*)(gA + it*128),
                                     (LDS_AS void*)lA, 16, 0, 0);
    #pragma unroll
    for (int p=0;p<4;++p)
      __builtin_amdgcn_global_load_lds((const GLOBAL_AS void*)(gB + it*128 + p*32),
                                       (LDS_AS void*)(lB + (size_t)p*2048), 16, 0, 0);
    __syncthreads();
    #pragma unroll
    for (int p=0;p<4;++p){
      f16x8 a  = *(const f16x8*)&Asl[(size_t)p*512 + l16*32 + quad*8];
      f16x8 bf = *(const f16x8*)&Bsl[(size_t)p*2048 + (w*16+l16)*32 + quad*8];
      acc = __builtin_amdgcn_mfma_f32_16x16x32_f16(a, bf, acc, 0, 0, 0);
    }
    __syncthreads();
  }
  // D: row m=quad*4+r (slot), col n=l16 -> d = d0 + w*16 + l16
  int dcol = d0 + w*16 + l16;
  #pragma unroll
  for (int r=0;r<4;++r){
    int i = b*NSLOT + quad*4 + r;
    upd[(size_t)i*D_DIM + dcol] = acc[r] / rowsum[i];
  }
}

// ---------- LayerNorm over rows of width 768 ----------
template<bool ADD, int OUT>
__global__ __launch_bounds__(256) void ln_k(
    const float* __restrict__ X, const float* __restrict__ X2,
    const float* __restrict__ g, const float* __restrict__ bb,
    void* __restrict__ out)
{
  __shared__ float rs[256], rss[256];
  const int row = blockIdx.x, tid = threadIdx.x;
  const float* x = X + (size_t)row*D_DIM;
  float vals[3]; float s=0.f, ss=0.f;
  #pragma unroll
  for (int t=0;t<3;++t){
    int c = tid + t*256;
    float v = x[c];
    if (ADD) v += X2[(size_t)row*D_DIM + c];
    vals[t]=v; s+=v; ss+=v*v;
  }
  rs[tid]=s; rss[tid]=ss; __syncthreads();
  for (int off=128; off>0; off>>=1){
    if (tid<off){ rs[tid]+=rs[tid+off]; rss[tid]+=rss[tid+off]; }
    __syncthreads();
  }
  float mean = rs[0]*(1.0f/768.0f);
  float var  = rss[0]*(1.0f/768.0f) - mean*mean;
  float inv  = rsqrtf(var + 1e-5f);
  #pragma unroll
  for (int t=0;t<3;++t){
    int c = tid + t*256;
    float y = (vals[t]-mean)*inv*g[c] + bb[c];
    if (OUT==1) ((f16*)out)[(size_t)row*D_DIM + c] = (f16)y;
    else        ((float*)out)[(size_t)row*D_DIM + c] = y;
  }
}

// ---------- fused double LayerNorm ----------
template<bool ADD>
__global__ __launch_bounds__(256) void lnln_k(
    const float* __restrict__ X, const float* __restrict__ X2,
    const float* __restrict__ g1, const float* __restrict__ b1,
    const float* __restrict__ g2, const float* __restrict__ b2,
    float* __restrict__ out1, f16* __restrict__ out2)
{
  __shared__ float rs[256], rss[256];
  const int row = blockIdx.x, tid = threadIdx.x;
  const float* x = X + (size_t)row*D_DIM;
  float vals[3]; float s=0.f, ss=0.f;
  #pragma unroll
  for (int t=0;t<3;++t){
    int c = tid + t*256;
    float v = x[c];
    if (ADD) v += X2[(size_t)row*D_DIM + c];
    vals[t]=v; s+=v; ss+=v*v;
  }
  rs[tid]=s; rss[tid]=ss; __syncthreads();
  for (int off=128; off>0; off>>=1){
    if (tid<off){ rs[tid]+=rs[tid+off]; rss[tid]+=rss[tid+off]; }
    __syncthreads();
  }
  float mean = rs[0]*(1.0f/768.0f);
  float var  = rss[0]*(1.0f/768.0f) - mean*mean;
  float inv  = rsqrtf(var + 1e-5f);
  float y[3]; float s2=0.f, ss2=0.f;
  #pragma unroll
  for (int t=0;t<3;++t){
    int c = tid + t*256;
    float yy = (vals[t]-mean)*inv*g1[c] + b1[c];
    y[t]=yy; s2+=yy; ss2+=yy*yy;
    out1[(size_t)row*D_DIM + c] = yy;
  }
  __syncthreads();
  rs[tid]=s2; rss[tid]=ss2; __syncthreads();
  for (int off=128; off>0; off>>=1){
    if (tid<off){ rs[tid]+=rs[tid+off]; rss[tid]+=rss[tid+off]; }
    __syncthreads();
  }
  float mean2 = rs[0]*(1.0f/768.0f);
  float var2  = rss[0]*(1.0f/768.0f) - mean2*mean2;
  float inv2  = rsqrtf(var2 + 1e-5f);
  #pragma unroll
  for (int t=0;t<3;++t){
    int c = tid + t*256;
    out2[(size_t)row*D_DIM + c] = (f16)((y[t]-mean2)*inv2*g2[c] + b2[c]);
  }
}

// ---------- slots init ----------
__global__ __launch_bounds__(256) void slots_init_k(
    const float* __restrict__ noise, const float* __restrict__ mu,
    const float* __restrict__ ls, float* __restrict__ slots)
{
  int idx = blockIdx.x*256 + threadIdx.x;
  int d = idx % D_DIM;
  slots[idx] = mu[d] + expf(ls[d]) * noise[idx];
}

// ---------- encoder self-attention ----------
__global__ __launch_bounds__(256) void encattn_k(
    const f16* __restrict__ QA, const f16* __restrict__ KA,
    const f16* __restrict__ VA, int QSTR,
    f16* __restrict__ O)
{
  __shared__ float qs[16][68], ks[16][68], vs[16][68], ps[16][20];
  const int b = blockIdx.x, h = blockIdx.y;
  const int tid = threadIdx.x;
  {
    int i = tid>>4, dd=(tid&15)*4;
    size_t base = ((size_t)(b*NSLOT+i))*QSTR + h*64 + dd;
    f16x4 uq = *(const f16x4*)(QA + base);
    f16x4 uk = *(const f16x4*)(KA + base);
    f16x4 uv = *(const f16x4*)(VA + base);
    float4 fq = { (float)uq.x, (float)uq.y, (float)uq.z, (float)uq.w };
    float4 fk = { (float)uk.x, (float)uk.y, (float)uk.z, (float)uk.w };
    float4 fv = { (float)uv.x, (float)uv.y, (float)uv.z, (float)uv.w };
    *(float4*)&qs[i][dd]=fq; *(float4*)&ks[i][dd]=fk; *(float4*)&vs[i][dd]=fv;
  }
  __syncthreads();
  {
    int i = tid>>4, j = tid&15;
    float s=0.f;
    #pragma unroll 8
    for (int d=0; d<64; ++d) s += qs[i][d]*ks[j][d];
    ps[i][j] = s*SCALE_H;
  }
  __syncthreads();
  if (tid < 16){
    int i = tid;
    float mx=-1e30f;
    #pragma unroll
    for (int j=0;j<16;++j) mx = fmaxf(mx, ps[i][j]);
    float sm=0.f;
    #pragma unroll
    for (int j=0;j<16;++j){ float e=__expf(ps[i][j]-mx); ps[i][j]=e; sm+=e; }
    float inv=1.0f/sm;
    #pragma unroll
    for (int j=0;j<16;++j) ps[i][j]*=inv;
  }
  __syncthreads();
  {
    int i = tid>>4, dq=(tid&15)*4;
    float a0=0,a1=0,a2=0,a3=0;
    #pragma unroll
    for (int j=0;j<16;++j){
      float p = ps[i][j];
      a0+=p*vs[j][dq+0]; a1+=p*vs[j][dq+1]; a2+=p*vs[j][dq+2]; a3+=p*vs[j][dq+3];
    }
    size_t base = ((size_t)(b*NSLOT+i))*HDIM + h*64 + dq;
    O[base+0]=(f16)a0; O[base+1]=(f16)a1; O[base+2]=(f16)a2; O[base+3]=(f16)a3;
  }
}

// ---------- f32 -> f16 transposed cast ----------
__global__ __launch_bounds__(256) void cast_t_k(
    const float* __restrict__ in, f16* __restrict__ out, int R, int C)
{
  __shared__ float t[32][33];
  int r0 = blockIdx.x*32, c0 = blockIdx.y*32;
  int tr = threadIdx.x & 31, g8 = threadIdx.x >> 5;
  #pragma unroll
  for (int s=0;s<4;++s){
    int r = g8*4 + s;
    t[r][tr] = in[(size_t)(r0+r)*C + c0+tr];
  }
  __syncthreads();
  #pragma unroll
  for (int s=0;s<4;++s){
    int c = g8*4+s;
    out[(size_t)(c0+c)*R + r0+tr] = (f16)t[tr][c];
  }
}

// ---------- attn_map output ----------
__global__ __launch_bounds__(256) void attnout_k(
    const f16* __restrict__ attn, const float* __restrict__ rowsum,
    float* __restrict__ out)
{
  int idx = blockIdx.x*256 + threadIdx.x;  // 32*1024*16
  int i = idx & 15;
  int j = (idx >> 4) & 1023;
  int b = idx >> 14;
  out[idx] = (float)attn[((size_t)b*NSLOT+i)*NTOK + j] / rowsum[b*NSLOT + i];
}

extern "C" void kernel_launch(void* const* d_in, const int* in_sizes, int n_in,
                              void* d_out, int out_size, void* d_ws, size_t ws_size,
                              hipStream_t stream) {
  const float* x        = (const float*)d_in[0];
  const float* noise    = (const float*)d_in[1];
  const float* init_mu  = (const float*)d_in[2];
  const float* init_ls  = (const float*)d_in[3];
  const float* Wk       = (const float*)d_in[4];
  const float* Wv       = (const float*)d_in[5];
  const float* Wq       = (const float*)d_in[6];
  const float* ni_g     = (const float*)d_in[7];
  const float* ni_b     = (const float*)d_in[8];
  const float* ns_g     = (const float*)d_in[9];
  const float* ns_b     = (const float*)d_in[10];
  const float* nica_g   = (const float*)d_in[11];
  const float* nica_b   = (const float*)d_in[12];
  const float* ln1_g    = (const float*)d_in[13];
  const float* ln1_b    = (const float*)d_in[14];
  const float* Wq_a     = (const float*)d_in[15];
  const float* Wk_a     = (const float*)d_in[16];
  const float* Wv_a     = (const float*)d_in[17];
  const float* Wo_a     = (const float*)d_in[18];
  const float* ln2_g    = (const float*)d_in[19];
  const float* ln2_b    = (const float*)d_in[20];
  const float* W1       = (const float*)d_in[21];
  const float* W2       = (const float*)d_in[22];
  const float* lnf_g    = (const float*)d_in[23];
  const float* lnf_b    = (const float*)d_in[24];

  char* w = (char*)d_ws;
  size_t off = 0;
  auto alloc = [&](size_t bytes)->char*{
    char* p = w + off; off += (bytes + 255) & ~(size_t)255; return p;
  };
  f16* xn_h  = (f16*)alloc((size_t)NTOT*D_DIM*2);     // 48 MB
  f16* k_h   = (f16*)alloc((size_t)NTOT*D_DIM*2);     // 48 MB
  f16* vT_h  = (f16*)alloc((size_t)D_DIM*NTOT*2);     // 48 MB
  f16* WkvT  = (f16*)alloc((size_t)1536*768*2);
  f16* WqT   = (f16*)alloc((size_t)768*768*2);
  f16* WqkvT = (f16*)alloc((size_t)1536*768*2);
  f16* WoaT  = (f16*)alloc((size_t)768*512*2);
  f16* W1T   = (f16*)alloc((size_t)6144*768*2);
  f16* W2T   = (f16*)alloc((size_t)768*3072*2);
  float* slots = (float*)alloc(512*768*4);
  float* hbuf  = (float*)alloc(512*768*4);
  float* upd   = (float*)alloc(512*768*4);
  f16* tmp_h  = (f16*)alloc(512*768*2);
  f16* tmp2_h = (f16*)alloc(512*768*2);
  f16* q_h    = (f16*)alloc(512*768*2);
  f16* qkv_h  = (f16*)alloc((size_t)512*1536*2);
  f16* o_h    = (f16*)alloc(512*512*2);
  f16* act_h  = (f16*)alloc((size_t)512*3072*2);
  f16* attn_h = (f16*)alloc((size_t)NB*NSLOT*NTOK*2);
  float* rowsum = (float*)alloc(512*4);

  auto castT = [&](const float* src, f16* dst, int R, int C){
    cast_t_k<<<dim3(R/32, C/32), 256, 0, stream>>>(src, dst, R, C);
  };
  castT(Wk,   WkvT,            768, 768);
  castT(Wv,   WkvT + 768*768,  768, 768);
  castT(Wq,   WqT,             768, 768);
  castT(Wq_a, WqkvT,             768, 512);
  castT(Wk_a, WqkvT + 512*768,   768, 512);
  castT(Wv_a, WqkvT + 1024*768,  768, 512);
  castT(Wo_a, WoaT,            512, 768);
  castT(W1,   W1T,             768, 6144);
  castT(W2,   W2T,             3072, 768);

  // xn = LN(x); [k | vT] = xn @ [Wk|Wv]
  ln_k<false,1><<<NTOT, 256, 0, stream>>>(x, nullptr, ni_g, ni_b, xn_h);
  mgemm128_k<<<dim3(1536/128, NTOT/128), 256, 0, stream>>>(xn_h, WkvT, k_h, vT_h, NTOT, 768);

  slots_init_k<<<512*768/256, 256, 0, stream>>>(noise, init_mu, init_ls, slots);
  ln_k<false,1><<<512, 256, 0, stream>>>(slots, nullptr, ns_g, ns_b, tmp2_h);

  for (int it=0; it<4; ++it){
    hipMemsetAsync(rowsum, 0, 512*4, stream);
    // q = LN(slots,ns) @ Wq
    mgemm64_k<1><<<dim3(8, 12, 1), 256, 0, stream>>>(tmp2_h, WqT, q_h, 512, 768, 768, 768);
    // dots + inverted softmax (MFMA, BK=128)
    dots_k<<<dim3(NB, 16), 256, 0, stream>>>(q_h, k_h, attn_h, rowsum);
    // updates = (attn @ v) / rowsum  (MFMA on vT)
    attnv_k<<<dim3(NB, 12), 256, 0, stream>>>(attn_h, rowsum, vT_h, upd);
    // h = LN(slots+upd, nica) ; a = LN(h, ln1)
    lnln_k<true><<<512, 256, 0, stream>>>(slots, upd, nica_g, nica_b, ln1_g, ln1_b, hbuf, tmp_h);
    // qkv = a @ [Wq_a|Wk_a|Wv_a]
    mgemm64_k<1><<<dim3(8, 24, 1), 256, 0, stream>>>(tmp_h, WqkvT, qkv_h, 512, 1536, 768, 768);
    encattn_k<<<dim3(NB, 8), 256, 0, stream>>>(qkv_h, qkv_h + 512, qkv_h + 1024, 1536, o_h);
    // h += o @ Wo_a (split-K=2 atomic)
    mgemm64_k<2><<<dim3(8, 12, 2), 256, 0, stream>>>(o_h, WoaT, hbuf, 512, 768, 512, 256);
    // f = LN(h, ln2)
    ln_k<false,1><<<512, 256, 0, stream>>>(hbuf, nullptr, ln2_g, ln2_b, tmp_h);
    // act = glu(f @ W1)
    w1glu_k<<<dim3(8, 48), 256, 0, stream>>>(tmp_h, W1T, act_h, 512);
    // h += act @ W2 (split-K=4 atomic)
    mgemm64_k<2><<<dim3(8, 12, 4), 256, 0, stream>>>(act_h, W2T, hbuf, 512, 768, 3072, 768);
    // slots = LN(h, lnf); tmp2 = LN(slots, ns)
    lnln_k<false><<<512, 256, 0, stream>>>(hbuf, nullptr, lnf_g, lnf_b, ns_g, ns_b, slots, tmp2_h);
  }

  hipMemcpyAsync(d_out, slots, (size_t)512*768*4, hipMemcpyDeviceToDevice, stream);
  attnout_k<<<NB*NTOK*NSLOT/256, 256, 0, stream>>>(attn_h, rowsum, (float*)d_out + 512*768);
}

// Round 6
// 668.295 us; speedup vs baseline: 5.6448x; 1.1107x over previous
//
#include <hip/hip_runtime.h>
#include <hip/hip_bf16.h>
#include <stdint.h>

typedef _Float16 f16;
typedef __attribute__((ext_vector_type(8))) _Float16 f16x8;
typedef __attribute__((ext_vector_type(4))) _Float16 f16x4;
typedef __attribute__((ext_vector_type(4))) float f32x4;

#define GLOBAL_AS __attribute__((address_space(1)))
#define LDS_AS __attribute__((address_space(3)))

#define D_DIM 768
#define NTOK 1024
#define NSLOT 16
#define NB 32
#define NTOT (NB*NTOK)   // 32768
#define HDIM 512
#define INNER 3072
#define SCALE_D 0.03608439182435161f   // 768^-0.5
#define SCALE_H 0.125f                 // 64^-0.5

// ---------- MFMA GEMM 64x64, BK=128 (4 panels), split-K ----------
// OUT: 0 = f32 store, 1 = f16 store, 2 = f32 atomicAdd.
template<int OUT>
__global__ __launch_bounds__(256) void mgemm64_k(
    const f16* __restrict__ A, const f16* __restrict__ Bt,
    void* __restrict__ Cout, int M, int N, int K, int Kc)
{
  __shared__ __align__(16) f16 As[64*128];
  __shared__ __align__(16) f16 Bs[64*128];
  const int tid = threadIdx.x;
  const int lane = tid & 63;
  const int wave = tid >> 6;
  const int m0 = blockIdx.x*64, n0 = blockIdx.y*64;
  const int kbeg = blockIdx.z * Kc;
  const int wm = (wave>>1)*32, wn = (wave&1)*32;
  const int quad = lane>>4, l16 = lane&15;

  const int sr = tid>>2;
  const int sc = (tid&3)*8;
  const f16* gA = A  + (size_t)(m0+sr)*K + kbeg + sc;
  const f16* gB = Bt + (size_t)(n0+sr)*K + kbeg + sc;
  LDS_AS f16* lA = (LDS_AS f16*)&As[(size_t)tid*8];
  LDS_AS f16* lB = (LDS_AS f16*)&Bs[(size_t)tid*8];

  const f16* fA0 = &As[(wm + l16)*32 + quad*8];
  const f16* fB0 = &Bs[(wn + l16)*32 + quad*8];

  f32x4 acc[2][2] = {};

  for (int k0 = 0; k0 < Kc; k0 += 128){
    #pragma unroll
    for (int p=0;p<4;++p){
      __builtin_amdgcn_global_load_lds((const GLOBAL_AS void*)(gA + k0 + p*32),
                                       (LDS_AS void*)(lA + (size_t)p*2048), 16, 0, 0);
      __builtin_amdgcn_global_load_lds((const GLOBAL_AS void*)(gB + k0 + p*32),
                                       (LDS_AS void*)(lB + (size_t)p*2048), 16, 0, 0);
    }
    __syncthreads();
    #pragma unroll
    for (int p=0;p<4;++p){
      f16x8 a0 = *(const f16x8*)(fA0 + p*2048);
      f16x8 a1 = *(const f16x8*)(fA0 + p*2048 + 16*32);
      f16x8 b0 = *(const f16x8*)(fB0 + p*2048);
      f16x8 b1 = *(const f16x8*)(fB0 + p*2048 + 16*32);
      acc[0][0] = __builtin_amdgcn_mfma_f32_16x16x32_f16(a0,b0,acc[0][0],0,0,0);
      acc[0][1] = __builtin_amdgcn_mfma_f32_16x16x32_f16(a0,b1,acc[0][1],0,0,0);
      acc[1][0] = __builtin_amdgcn_mfma_f32_16x16x32_f16(a1,b0,acc[1][0],0,0,0);
      acc[1][1] = __builtin_amdgcn_mfma_f32_16x16x32_f16(a1,b1,acc[1][1],0,0,0);
    }
    __syncthreads();
  }
  #pragma unroll
  for (int mt=0;mt<2;++mt){
    #pragma unroll
    for (int nt=0;nt<2;++nt){
      int gm = m0 + wm + mt*16 + quad*4;
      int gn = n0 + wn + nt*16 + l16;
      #pragma unroll
      for (int r=0;r<4;++r){
        float c = acc[mt][nt][r];
        size_t idx = (size_t)(gm+r)*N + gn;
        if (OUT==0)      ((float*)Cout)[idx] = c;
        else if (OUT==1) ((f16*)Cout)[idx] = (f16)c;
        else             atomicAdd(&((float*)Cout)[idx], c);
      }
    }
  }
}

// ---------- W1 + GLU fused ----------
__global__ __launch_bounds__(256) void w1glu_k(
    const f16* __restrict__ A, const f16* __restrict__ W1T,
    f16* __restrict__ act, int M)
{
  __shared__ __align__(16) f16 As[64*128];
  __shared__ __align__(16) f16 Bu[64*128];
  __shared__ __align__(16) f16 Bg[64*128];
  const int K = 768;
  const int tid = threadIdx.x;
  const int lane = tid & 63;
  const int wave = tid >> 6;
  const int m0 = blockIdx.x*64, n0 = blockIdx.y*64;
  const int wm = (wave>>1)*32, wn = (wave&1)*32;
  const int quad = lane>>4, l16 = lane&15;

  const int sr = tid>>2;
  const int sc = (tid&3)*8;
  const f16* gA  = A   + (size_t)(m0+sr)*K + sc;
  const f16* gBu = W1T + (size_t)(n0+sr)*K + sc;
  const f16* gBg = W1T + (size_t)(3072+n0+sr)*K + sc;
  LDS_AS f16* lA  = (LDS_AS f16*)&As[(size_t)tid*8];
  LDS_AS f16* lBu = (LDS_AS f16*)&Bu[(size_t)tid*8];
  LDS_AS f16* lBg = (LDS_AS f16*)&Bg[(size_t)tid*8];

  const f16* fA0 = &As[(wm + l16)*32 + quad*8];
  const f16* fU0 = &Bu[(wn + l16)*32 + quad*8];
  const f16* fG0 = &Bg[(wn + l16)*32 + quad*8];

  f32x4 accU[2][2] = {};
  f32x4 accG[2][2] = {};

  for (int k0 = 0; k0 < K; k0 += 128){
    #pragma unroll
    for (int p=0;p<4;++p){
      __builtin_amdgcn_global_load_lds((const GLOBAL_AS void*)(gA  + k0 + p*32),
                                       (LDS_AS void*)(lA  + (size_t)p*2048), 16, 0, 0);
      __builtin_amdgcn_global_load_lds((const GLOBAL_AS void*)(gBu + k0 + p*32),
                                       (LDS_AS void*)(lBu + (size_t)p*2048), 16, 0, 0);
      __builtin_amdgcn_global_load_lds((const GLOBAL_AS void*)(gBg + k0 + p*32),
                                       (LDS_AS void*)(lBg + (size_t)p*2048), 16, 0, 0);
    }
    __syncthreads();
    #pragma unroll
    for (int p=0;p<4;++p){
      f16x8 a0 = *(const f16x8*)(fA0 + p*2048);
      f16x8 a1 = *(const f16x8*)(fA0 + p*2048 + 16*32);
      f16x8 u0 = *(const f16x8*)(fU0 + p*2048);
      f16x8 u1 = *(const f16x8*)(fU0 + p*2048 + 16*32);
      f16x8 g0 = *(const f16x8*)(fG0 + p*2048);
      f16x8 g1 = *(const f16x8*)(fG0 + p*2048 + 16*32);
      accU[0][0] = __builtin_amdgcn_mfma_f32_16x16x32_f16(a0,u0,accU[0][0],0,0,0);
      accU[0][1] = __builtin_amdgcn_mfma_f32_16x16x32_f16(a0,u1,accU[0][1],0,0,0);
      accU[1][0] = __builtin_amdgcn_mfma_f32_16x16x32_f16(a1,u0,accU[1][0],0,0,0);
      accU[1][1] = __builtin_amdgcn_mfma_f32_16x16x32_f16(a1,u1,accU[1][1],0,0,0);
      accG[0][0] = __builtin_amdgcn_mfma_f32_16x16x32_f16(a0,g0,accG[0][0],0,0,0);
      accG[0][1] = __builtin_amdgcn_mfma_f32_16x16x32_f16(a0,g1,accG[0][1],0,0,0);
      accG[1][0] = __builtin_amdgcn_mfma_f32_16x16x32_f16(a1,g0,accG[1][0],0,0,0);
      accG[1][1] = __builtin_amdgcn_mfma_f32_16x16x32_f16(a1,g1,accG[1][1],0,0,0);
    }
    __syncthreads();
  }
  #pragma unroll
  for (int mt=0;mt<2;++mt){
    #pragma unroll
    for (int nt=0;nt<2;++nt){
      int gm = m0 + wm + mt*16 + quad*4;
      int gn = n0 + wn + nt*16 + l16;
      #pragma unroll
      for (int r=0;r<4;++r){
        float u = accU[mt][nt][r];
        float g = accG[mt][nt][r];
        float sg = g / (1.0f + __expf(-g));
        act[(size_t)(gm+r)*INNER + gn] = (f16)(u*sg);
      }
    }
  }
}

// ---------- MFMA dots (q_eff @ xn^T) + inverted softmax + EPS + partial rowsum ----------
// grid (32, 16): batch x 64-j tile.
__global__ __launch_bounds__(256) void dots_k(
    const f16* __restrict__ Q,    // [32,16,768] q_eff
    const f16* __restrict__ Xn,   // [32768,768]
    f16* __restrict__ attn,       // [32,16,1024] f16
    float* __restrict__ rsPart)   // [32][16 jt][16 i]
{
  __shared__ __align__(16) f16 qf[16*768];    // A-frag layout, 24 KB
  __shared__ __align__(16) f16 ks[64*128];    // 4 panels [64][32], 16 KB
  __shared__ float rpart[4][16];
  const int b = blockIdx.x, jt = blockIdx.y;
  const int tid = threadIdx.x;
  const int lane = tid & 63;
  const int w = tid >> 6;
  const int quad = lane>>4, l16 = lane&15;

  #pragma unroll
  for (int c=0;c<6;++c){
    int p = c*256 + tid;
    int ki = p >> 6, qd = (p >> 4) & 3, rw = p & 15;
    f16x8 v = *(const f16x8*)(Q + ((size_t)(b*NSLOT+rw))*D_DIM + ki*32 + qd*8);
    *(f16x8*)&qf[(size_t)p*8] = v;
  }

  const f16* gK = Xn + ((size_t)(b*NTOK + jt*64 + (tid>>2)))*D_DIM + (tid&3)*8;
  LDS_AS f16* lK = (LDS_AS f16*)&ks[(size_t)tid*8];

  f32x4 acc = {};
  for (int it=0; it<6; ++it){
    #pragma unroll
    for (int p=0;p<4;++p)
      __builtin_amdgcn_global_load_lds((const GLOBAL_AS void*)(gK + it*128 + p*32),
                                       (LDS_AS void*)(lK + (size_t)p*2048), 16, 0, 0);
    __syncthreads();
    #pragma unroll
    for (int p=0;p<4;++p){
      f16x8 a  = *(const f16x8*)&qf[(((size_t)(it*4+p)*4 + quad)*16 + l16)*8];
      f16x8 bf = *(const f16x8*)&ks[(size_t)p*2048 + (w*16+l16)*32 + quad*8];
      acc = __builtin_amdgcn_mfma_f32_16x16x32_f16(a, bf, acc, 0, 0, 0);
    }
    __syncthreads();
  }

  float v0 = acc[0]*SCALE_D, v1 = acc[1]*SCALE_D, v2 = acc[2]*SCALE_D, v3 = acc[3]*SCALE_D;
  float mx = fmaxf(fmaxf(v0,v1), fmaxf(v2,v3));
  mx = fmaxf(mx, __shfl_xor(mx, 16));
  mx = fmaxf(mx, __shfl_xor(mx, 32));
  float e0 = __expf(v0-mx), e1 = __expf(v1-mx), e2 = __expf(v2-mx), e3 = __expf(v3-mx);
  float s = e0+e1+e2+e3;
  s += __shfl_xor(s, 16);
  s += __shfl_xor(s, 32);
  float inv = 1.0f/s;
  float a0 = e0*inv + 1e-8f, a1 = e1*inv + 1e-8f, a2 = e2*inv + 1e-8f, a3 = e3*inv + 1e-8f;

  int jcol = jt*64 + w*16 + l16;
  int ibase = b*NSLOT + quad*4;
  attn[(size_t)(ibase+0)*NTOK + jcol] = (f16)a0;
  attn[(size_t)(ibase+1)*NTOK + jcol] = (f16)a1;
  attn[(size_t)(ibase+2)*NTOK + jcol] = (f16)a2;
  attn[(size_t)(ibase+3)*NTOK + jcol] = (f16)a3;

  float t0=a0, t1=a1, t2=a2, t3=a3;
  #pragma unroll
  for (int m=1;m<16;m<<=1){
    t0 += __shfl_xor(t0, m);
    t1 += __shfl_xor(t1, m);
    t2 += __shfl_xor(t2, m);
    t3 += __shfl_xor(t3, m);
  }
  if (l16 == 0){
    rpart[w][quad*4+0] = t0;
    rpart[w][quad*4+1] = t1;
    rpart[w][quad*4+2] = t2;
    rpart[w][quad*4+3] = t3;
  }
  __syncthreads();
  if (tid < 16){
    float ss = rpart[0][tid] + rpart[1][tid] + rpart[2][tid] + rpart[3][tid];
    rsPart[(size_t)((b*16 + jt)<<4) + tid] = ss;
  }
}

// ---------- t = (attn @ xn) / rowsum via MFMA on xnT; t -> f16 ----------
// grid (32 b, 12 d-tiles of 64).
__global__ __launch_bounds__(256) void attnv_k(
    const f16* __restrict__ attn,   // [32,16,1024] f16
    const float* __restrict__ rsPart,
    const f16* __restrict__ XnT,    // [768, 32768]
    f16* __restrict__ t_out)        // [32,16,768] f16
{
  __shared__ __align__(16) f16 Asl[16*128];
  __shared__ __align__(16) f16 Bsl[64*128];
  __shared__ float rsum[16];
  const int b = blockIdx.x, d0 = blockIdx.y*64;
  const int tid = threadIdx.x;
  const int lane = tid & 63;
  const int w = tid >> 6;
  const int quad = lane>>4, l16 = lane&15;

  if (tid < 16){
    float s = 0.f;
    #pragma unroll
    for (int jt=0;jt<16;++jt) s += rsPart[(size_t)((b*16 + jt)<<4) + tid];
    rsum[tid] = s;
  }

  const int pa = tid>>6, ta = tid&63;
  const f16* gA = attn + ((size_t)(b*NSLOT + (ta>>2)))*NTOK + pa*32 + (ta&3)*8;
  LDS_AS f16* lA = (LDS_AS f16*)&Asl[(size_t)pa*512 + ta*8];
  const f16* gB = XnT + ((size_t)(d0 + (tid>>2)))*NTOT + b*NTOK + (tid&3)*8;
  LDS_AS f16* lB = (LDS_AS f16*)&Bsl[(size_t)tid*8];

  f32x4 acc = {};
  for (int it=0; it<8; ++it){
    __builtin_amdgcn_global_load_lds((const GLOBAL_AS void*)(gA + it*128),
                                     (LDS_AS void*)lA, 16, 0, 0);
    #pragma unroll
    for (int p=0;p<4;++p)
      __builtin_amdgcn_global_load_lds((const GLOBAL_AS void*)(gB + it*128 + p*32),
                                       (LDS_AS void*)(lB + (size_t)p*2048), 16, 0, 0);
    __syncthreads();
    #pragma unroll
    for (int p=0;p<4;++p){
      f16x8 a  = *(const f16x8*)&Asl[(size_t)p*512 + l16*32 + quad*8];
      f16x8 bf = *(const f16x8*)&Bsl[(size_t)p*2048 + (w*16+l16)*32 + quad*8];
      acc = __builtin_amdgcn_mfma_f32_16x16x32_f16(a, bf, acc, 0, 0, 0);
    }
    __syncthreads();
  }
  int dcol = d0 + w*16 + l16;
  #pragma unroll
  for (int r=0;r<4;++r){
    int i = quad*4 + r;
    t_out[(size_t)(b*NSLOT + i)*D_DIM + dcol] = (f16)(acc[r] / rsum[i]);
  }
}

// ---------- LayerNorm over rows of width 768 ----------
template<bool ADD, int OUT>
__global__ __launch_bounds__(256) void ln_k(
    const float* __restrict__ X, const float* __restrict__ X2,
    const float* __restrict__ g, const float* __restrict__ bb,
    void* __restrict__ out)
{
  __shared__ float rs[256], rss[256];
  const int row = blockIdx.x, tid = threadIdx.x;
  const float* x = X + (size_t)row*D_DIM;
  float vals[3]; float s=0.f, ss=0.f;
  #pragma unroll
  for (int t=0;t<3;++t){
    int c = tid + t*256;
    float v = x[c];
    if (ADD) v += X2[(size_t)row*D_DIM + c];
    vals[t]=v; s+=v; ss+=v*v;
  }
  rs[tid]=s; rss[tid]=ss; __syncthreads();
  for (int off=128; off>0; off>>=1){
    if (tid<off){ rs[tid]+=rs[tid+off]; rss[tid]+=rss[tid+off]; }
    __syncthreads();
  }
  float mean = rs[0]*(1.0f/768.0f);
  float var  = rss[0]*(1.0f/768.0f) - mean*mean;
  float inv  = rsqrtf(var + 1e-5f);
  #pragma unroll
  for (int t=0;t<3;++t){
    int c = tid + t*256;
    float y = (vals[t]-mean)*inv*g[c] + bb[c];
    if (OUT==1) ((f16*)out)[(size_t)row*D_DIM + c] = (f16)y;
    else        ((float*)out)[(size_t)row*D_DIM + c] = y;
  }
}

// ---------- fused double LayerNorm ----------
template<bool ADD>
__global__ __launch_bounds__(256) void lnln_k(
    const float* __restrict__ X, const float* __restrict__ X2,
    const float* __restrict__ g1, const float* __restrict__ b1,
    const float* __restrict__ g2, const float* __restrict__ b2,
    float* __restrict__ out1, f16* __restrict__ out2)
{
  __shared__ float rs[256], rss[256];
  const int row = blockIdx.x, tid = threadIdx.x;
  const float* x = X + (size_t)row*D_DIM;
  float vals[3]; float s=0.f, ss=0.f;
  #pragma unroll
  for (int t=0;t<3;++t){
    int c = tid + t*256;
    float v = x[c];
    if (ADD) v += X2[(size_t)row*D_DIM + c];
    vals[t]=v; s+=v; ss+=v*v;
  }
  rs[tid]=s; rss[tid]=ss; __syncthreads();
  for (int off=128; off>0; off>>=1){
    if (tid<off){ rs[tid]+=rs[tid+off]; rss[tid]+=rss[tid+off]; }
    __syncthreads();
  }
  float mean = rs[0]*(1.0f/768.0f);
  float var  = rss[0]*(1.0f/768.0f) - mean*mean;
  float inv  = rsqrtf(var + 1e-5f);
  float y[3]; float s2=0.f, ss2=0.f;
  #pragma unroll
  for (int t=0;t<3;++t){
    int c = tid + t*256;
    float yy = (vals[t]-mean)*inv*g1[c] + b1[c];
    y[t]=yy; s2+=yy; ss2+=yy*yy;
    out1[(size_t)row*D_DIM + c] = yy;
  }
  __syncthreads();
  rs[tid]=s2; rss[tid]=ss2; __syncthreads();
  for (int off=128; off>0; off>>=1){
    if (tid<off){ rs[tid]+=rs[tid+off]; rss[tid]+=rss[tid+off]; }
    __syncthreads();
  }
  float mean2 = rs[0]*(1.0f/768.0f);
  float var2  = rss[0]*(1.0f/768.0f) - mean2*mean2;
  float inv2  = rsqrtf(var2 + 1e-5f);
  #pragma unroll
  for (int t=0;t<3;++t){
    int c = tid + t*256;
    out2[(size_t)row*D_DIM + c] = (f16)((y[t]-mean2)*inv2*g2[c] + b2[c]);
  }
}

// ---------- slots init ----------
__global__ __launch_bounds__(256) void slots_init_k(
    const float* __restrict__ noise, const float* __restrict__ mu,
    const float* __restrict__ ls, float* __restrict__ slots)
{
  int idx = blockIdx.x*256 + threadIdx.x;
  int d = idx % D_DIM;
  slots[idx] = mu[d] + expf(ls[d]) * noise[idx];
}

// ---------- encoder self-attention ----------
__global__ __launch_bounds__(256) void encattn_k(
    const f16* __restrict__ QA, const f16* __restrict__ KA,
    const f16* __restrict__ VA, int QSTR,
    f16* __restrict__ O)
{
  __shared__ float qs[16][68], ks[16][68], vs[16][68], ps[16][20];
  const int b = blockIdx.x, h = blockIdx.y;
  const int tid = threadIdx.x;
  {
    int i = tid>>4, dd=(tid&15)*4;
    size_t base = ((size_t)(b*NSLOT+i))*QSTR + h*64 + dd;
    f16x4 uq = *(const f16x4*)(QA + base);
    f16x4 uk = *(const f16x4*)(KA + base);
    f16x4 uv = *(const f16x4*)(VA + base);
    float4 fq = { (float)uq.x, (float)uq.y, (float)uq.z, (float)uq.w };
    float4 fk = { (float)uk.x, (float)uk.y, (float)uk.z, (float)uk.w };
    float4 fv = { (float)uv.x, (float)uv.y, (float)uv.z, (float)uv.w };
    *(float4*)&qs[i][dd]=fq; *(float4*)&ks[i][dd]=fk; *(float4*)&vs[i][dd]=fv;
  }
  __syncthreads();
  {
    int i = tid>>4, j = tid&15;
    float s=0.f;
    #pragma unroll 8
    for (int d=0; d<64; ++d) s += qs[i][d]*ks[j][d];
    ps[i][j] = s*SCALE_H;
  }
  __syncthreads();
  if (tid < 16){
    int i = tid;
    float mx=-1e30f;
    #pragma unroll
    for (int j=0;j<16;++j) mx = fmaxf(mx, ps[i][j]);
    float sm=0.f;
    #pragma unroll
    for (int j=0;j<16;++j){ float e=__expf(ps[i][j]-mx); ps[i][j]=e; sm+=e; }
    float inv=1.0f/sm;
    #pragma unroll
    for (int j=0;j<16;++j) ps[i][j]*=inv;
  }
  __syncthreads();
  {
    int i = tid>>4, dq=(tid&15)*4;
    float a0=0,a1=0,a2=0,a3=0;
    #pragma unroll
    for (int j=0;j<16;++j){
      float p = ps[i][j];
      a0+=p*vs[j][dq+0]; a1+=p*vs[j][dq+1]; a2+=p*vs[j][dq+2]; a3+=p*vs[j][dq+3];
    }
    size_t base = ((size_t)(b*NSLOT+i))*HDIM + h*64 + dq;
    O[base+0]=(f16)a0; O[base+1]=(f16)a1; O[base+2]=(f16)a2; O[base+3]=(f16)a3;
  }
}

// ---------- f32 -> f16 transposed cast ----------
__global__ __launch_bounds__(256) void cast_t_k(
    const float* __restrict__ in, f16* __restrict__ out, int R, int C)
{
  __shared__ float t[32][33];
  int r0 = blockIdx.x*32, c0 = blockIdx.y*32;
  int tr = threadIdx.x & 31, g8 = threadIdx.x >> 5;
  #pragma unroll
  for (int s=0;s<4;++s){
    int r = g8*4 + s;
    t[r][tr] = in[(size_t)(r0+r)*C + c0+tr];
  }
  __syncthreads();
  #pragma unroll
  for (int s=0;s<4;++s){
    int c = g8*4+s;
    out[(size_t)(c0+c)*R + r0+tr] = (f16)t[tr][c];
  }
}

// ---------- f32 -> f16 plain cast ----------
__global__ __launch_bounds__(256) void cast_k(
    const float* __restrict__ in, f16* __restrict__ out, int n)
{
  int i = blockIdx.x*256 + threadIdx.x;
  if (i < n) out[i] = (f16)in[i];
}

// ---------- f16 transpose: out[C][R] = in[R][C], R%64==0, C%64==0 ----------
__global__ __launch_bounds__(256) void transp_k(
    const f16* __restrict__ in, f16* __restrict__ out, int R, int C)
{
  __shared__ f16 T[64][72];   // row stride 144 B (16-aligned)
  const int m0 = blockIdx.x*64, d0 = blockIdx.y*64;
  const int tid = threadIdx.x;
  {
    int r = tid>>2, c = (tid&3)*16;
    const f16* p = in + (size_t)(m0+r)*C + d0 + c;
    *(f16x8*)&T[r][c]   = *(const f16x8*)p;
    *(f16x8*)&T[r][c+8] = *(const f16x8*)(p+8);
  }
  __syncthreads();
  {
    int dd = tid>>2, mq = (tid&3)*16;
    f16 v[16];
    #pragma unroll
    for (int e=0;e<16;++e) v[e] = T[mq+e][dd];
    f16* p = out + (size_t)(d0+dd)*R + m0 + mq;
    *(f16x8*)p     = *(f16x8*)&v[0];
    *(f16x8*)(p+8) = *(f16x8*)&v[8];
  }
}

// ---------- rowsum finalize ----------
__global__ __launch_bounds__(256) void rsfin_k(
    const float* __restrict__ rsPart, float* __restrict__ rowsum)
{
  int idx = blockIdx.x*256 + threadIdx.x;
  if (idx < 512){
    int b = idx>>4, i = idx&15;
    float s = 0.f;
    #pragma unroll
    for (int jt=0;jt<16;++jt) s += rsPart[(size_t)((b*16+jt)<<4) + i];
    rowsum[idx] = s;
  }
}

// ---------- attn_map output ----------
__global__ __launch_bounds__(256) void attnout_k(
    const f16* __restrict__ attn, const float* __restrict__ rowsum,
    float* __restrict__ out)
{
  int idx = blockIdx.x*256 + threadIdx.x;  // 32*1024*16
  int i = idx & 15;
  int j = (idx >> 4) & 1023;
  int b = idx >> 14;
  out[idx] = (float)attn[((size_t)b*NSLOT+i)*NTOK + j] / rowsum[b*NSLOT + i];
}

extern "C" void kernel_launch(void* const* d_in, const int* in_sizes, int n_in,
                              void* d_out, int out_size, void* d_ws, size_t ws_size,
                              hipStream_t stream) {
  const float* x        = (const float*)d_in[0];
  const float* noise    = (const float*)d_in[1];
  const float* init_mu  = (const float*)d_in[2];
  const float* init_ls  = (const float*)d_in[3];
  const float* Wk       = (const float*)d_in[4];
  const float* Wv       = (const float*)d_in[5];
  const float* Wq       = (const float*)d_in[6];
  const float* ni_g     = (const float*)d_in[7];
  const float* ni_b     = (const float*)d_in[8];
  const float* ns_g     = (const float*)d_in[9];
  const float* ns_b     = (const float*)d_in[10];
  const float* nica_g   = (const float*)d_in[11];
  const float* nica_b   = (const float*)d_in[12];
  const float* ln1_g    = (const float*)d_in[13];
  const float* ln1_b    = (const float*)d_in[14];
  const float* Wq_a     = (const float*)d_in[15];
  const float* Wk_a     = (const float*)d_in[16];
  const float* Wv_a     = (const float*)d_in[17];
  const float* Wo_a     = (const float*)d_in[18];
  const float* ln2_g    = (const float*)d_in[19];
  const float* ln2_b    = (const float*)d_in[20];
  const float* W1       = (const float*)d_in[21];
  const float* W2       = (const float*)d_in[22];
  const float* lnf_g    = (const float*)d_in[23];
  const float* lnf_b    = (const float*)d_in[24];

  char* w = (char*)d_ws;
  size_t off = 0;
  auto alloc = [&](size_t bytes)->char*{
    char* p = w + off; off += (bytes + 255) & ~(size_t)255; return p;
  };
  f16* xn_h  = (f16*)alloc((size_t)NTOT*D_DIM*2);     // 48 MB
  f16* xnT_h = (f16*)alloc((size_t)D_DIM*NTOT*2);     // 48 MB
  f16* Wkf   = (f16*)alloc((size_t)768*768*2);        // plain f16 cast of Wk [f][d]
  f16* Wqf   = (f16*)alloc((size_t)768*768*2);        // plain f16 cast of Wq [e][d]
  f16* BtQK  = (f16*)alloc((size_t)768*768*2);        // [f][e] = sum_d Wk[f][d]Wq[e][d]
  f16* WvT   = (f16*)alloc((size_t)768*768*2);
  f16* WqkvT = (f16*)alloc((size_t)1536*768*2);
  f16* WoaT  = (f16*)alloc((size_t)768*512*2);
  f16* W1T   = (f16*)alloc((size_t)6144*768*2);
  f16* W2T   = (f16*)alloc((size_t)768*3072*2);
  float* slots = (float*)alloc(512*768*4);
  float* hbuf  = (float*)alloc(512*768*4);
  float* upd   = (float*)alloc(512*768*4);
  f16* tmp_h  = (f16*)alloc(512*768*2);
  f16* tmp2_h = (f16*)alloc(512*768*2);
  f16* q_h    = (f16*)alloc(512*768*2);
  f16* t_h    = (f16*)alloc(512*768*2);
  f16* qkv_h  = (f16*)alloc((size_t)512*1536*2);
  f16* o_h    = (f16*)alloc(512*512*2);
  f16* act_h  = (f16*)alloc((size_t)512*3072*2);
  f16* attn_h = (f16*)alloc((size_t)NB*NSLOT*NTOK*2);
  float* rsPart = (float*)alloc((size_t)32*16*16*4);
  float* rowsum = (float*)alloc(512*4);

  auto castT = [&](const float* src, f16* dst, int R, int C){
    cast_t_k<<<dim3(R/32, C/32), 256, 0, stream>>>(src, dst, R, C);
  };
  cast_k<<<768*768/256, 256, 0, stream>>>(Wk, Wkf, 768*768);
  cast_k<<<768*768/256, 256, 0, stream>>>(Wq, Wqf, 768*768);
  castT(Wv,   WvT,             768, 768);
  castT(Wq_a, WqkvT,             768, 512);
  castT(Wk_a, WqkvT + 512*768,   768, 512);
  castT(Wv_a, WqkvT + 1024*768,  768, 512);
  castT(Wo_a, WoaT,            512, 768);
  castT(W1,   W1T,             768, 6144);
  castT(W2,   W2T,             3072, 768);

  // BtQK[f][e] = sum_d Wk[f][d] * Wq[e][d]
  mgemm64_k<1><<<dim3(12, 12, 1), 256, 0, stream>>>(Wkf, Wqf, BtQK, 768, 768, 768, 768);

  // xn = LN(x); xnT = xn^T
  ln_k<false,1><<<NTOT, 256, 0, stream>>>(x, nullptr, ni_g, ni_b, xn_h);
  transp_k<<<dim3(NTOT/64, D_DIM/64), 256, 0, stream>>>(xn_h, xnT_h, NTOT, D_DIM);

  slots_init_k<<<512*768/256, 256, 0, stream>>>(noise, init_mu, init_ls, slots);
  ln_k<false,1><<<512, 256, 0, stream>>>(slots, nullptr, ns_g, ns_b, tmp2_h);

  for (int it=0; it<4; ++it){
    // q_eff = LN(slots,ns) @ (Wq Wk^T)
    mgemm64_k<1><<<dim3(8, 12, 1), 256, 0, stream>>>(tmp2_h, BtQK, q_h, 512, 768, 768, 768);
    // dots = q_eff @ xn^T + inverted softmax
    dots_k<<<dim3(NB, 16), 256, 0, stream>>>(q_h, xn_h, attn_h, rsPart);
    // t = (attn @ xn) / rowsum
    attnv_k<<<dim3(NB, 12), 256, 0, stream>>>(attn_h, rsPart, xnT_h, t_h);
    // upd = t @ Wv
    mgemm64_k<0><<<dim3(8, 12, 1), 256, 0, stream>>>(t_h, WvT, upd, 512, 768, 768, 768);
    // h = LN(slots+upd, nica) ; a = LN(h, ln1)
    lnln_k<true><<<512, 256, 0, stream>>>(slots, upd, nica_g, nica_b, ln1_g, ln1_b, hbuf, tmp_h);
    // qkv = a @ [Wq_a|Wk_a|Wv_a]
    mgemm64_k<1><<<dim3(8, 24, 1), 256, 0, stream>>>(tmp_h, WqkvT, qkv_h, 512, 1536, 768, 768);
    encattn_k<<<dim3(NB, 8), 256, 0, stream>>>(qkv_h, qkv_h + 512, qkv_h + 1024, 1536, o_h);
    // h += o @ Wo_a (split-K=2 atomic)
    mgemm64_k<2><<<dim3(8, 12, 2), 256, 0, stream>>>(o_h, WoaT, hbuf, 512, 768, 512, 256);
    // f = LN(h, ln2)
    ln_k<false,1><<<512, 256, 0, stream>>>(hbuf, nullptr, ln2_g, ln2_b, tmp_h);
    // act = glu(f @ W1)
    w1glu_k<<<dim3(8, 48), 256, 0, stream>>>(tmp_h, W1T, act_h, 512);
    // h += act @ W2 (split-K=4 atomic)
    mgemm64_k<2><<<dim3(8, 12, 4), 256, 0, stream>>>(act_h, W2T, hbuf, 512, 768, 3072, 768);
    // slots = LN(h, lnf); tmp2 = LN(slots, ns)
    lnln_k<false><<<512, 256, 0, stream>>>(hbuf, nullptr, lnf_g, lnf_b, ns_g, ns_b, slots, tmp2_h);
  }

  hipMemcpyAsync(d_out, slots, (size_t)512*768*4, hipMemcpyDeviceToDevice, stream);
  rsfin_k<<<2, 256, 0, stream>>>(rsPart, rowsum);
  attnout_k<<<NB*NTOK*NSLOT/256, 256, 0, stream>>>(attn_h, rowsum, (float*)d_out + 512*768);
}